// Round 13
// baseline (366.436 us; speedup 1.0000x reference)
//
#include <hip/hip_runtime.h>
#include <stdint.h>

typedef __bf16 bf16_t;
typedef __bf16 bf16x8 __attribute__((ext_vector_type(8)));
typedef float f32x4 __attribute__((ext_vector_type(4)));

#define EPSBN 1e-5f

// ---------------- workspace layout (bytes) ----------------
#define OFF_XP   ((size_t)0)
#define SZ_IMG   ((size_t)8*4356*256*2)          // padded NHWC bf16 image, 66x66
#define OFF_YP   (OFF_XP + SZ_IMG)
#define OFF_WQS  (OFF_YP + SZ_IMG)
#define SZ_WQS   ((size_t)4*1024*2304*2)         // scaled QK conv weights [conv][hd][tap*256+c]
#define OFF_WVT  (OFF_WQS + SZ_WQS)
#define SZ_WVT   ((size_t)2*2304*1024*2)         // scaled V weights transposed [br][k'][hd]
#define OFF_W1B  (OFF_WVT + SZ_WVT)
#define SZ_WO    ((size_t)65536*2)
#define OFF_W2B  (OFF_W1B + SZ_WO)
#define OFF_SHQ  (OFF_W2B + SZ_WO)
#define SZ_SHQ   ((size_t)4096*4)                // BN shift for convs 0..3
#define OFF_SHV  (OFF_SHQ + SZ_SHQ)
#define SZ_SHV   ((size_t)2048*4)                // BN shift for convs 4,5
#define OFF_QK   (OFF_SHV + SZ_SHV)
#define SZ_QK    ((size_t)4*8*1024*1024*2)       // Q1,Q2,K1,K2: [conv][b][hd][tok] bf16
#define OFF_S    (OFF_QK + SZ_QK)
#define SZ_S     ((size_t)2*8*4*65536*4)         // scores f32 [br][b][h][c][d]
#define OFF_PT   (OFF_S + SZ_S)
#define SZ_PT    ((size_t)2*8*4*65536*2)         // p^T bf16 [br][b][h][d][c]  (x0.25, /l folded)
#define OFF_A1   (OFF_PT + SZ_PT)
#define SZ_A1    ((size_t)2*8*256*1024*2)        // A1 bf16 [br][b][e][hd]
#define OFF_WEFF (OFF_A1 + SZ_A1)
#define SZ_WEFF  ((size_t)2*8*256*2304*2)        // Weff bf16 [br][b][e][k']
#define OFF_BIAS (OFF_WEFF + SZ_WEFF)
#define SZ_BIAS  ((size_t)2*8*256*4)
#define WS_NEED  (OFF_BIAS + SZ_BIAS)

__device__ __forceinline__ void gload16(const bf16_t* g, bf16_t* l) {
  __builtin_amdgcn_global_load_lds(
      (const __attribute__((address_space(1))) void*)g,
      (__attribute__((address_space(3))) void*)l,
      16, 0, 0);
}

// staging LDS offsets for the B tile (wave wv owns chunks {wv, wv+4})
__device__ __forceinline__ int lb_off0() { return ((threadIdx.x >> 6)    ) * 512; }
__device__ __forceinline__ int lb_off1() { return ((threadIdx.x >> 6) + 4) * 512; }

#define SBAR0 __builtin_amdgcn_sched_barrier(0)

// ---------------- old GEMM core: 128x128 tile, BK=32, 4 waves (small GEMMs) ----------------
template<int BSRC>
__device__ __forceinline__ void gemm_core(
    const bf16_t* __restrict__ A, int ldA,
    const bf16_t* __restrict__ B, int ldB,
    int m0, int n0, int KT, f32x4 acc[4][4])
{
  __shared__ bf16_t lA[2][4096];
  __shared__ bf16_t lB[2][4096];
  const int tid  = threadIdx.x;
  const int lane = tid & 63;
  const int wv   = tid >> 6;
  const int wr   = wv >> 1, wc = wv & 1;
  const int r4   = lane >> 2;       // 0..15
  const int k8   = (lane & 3) * 8;  // 0,8,16,24

  const bf16_t* gA0 = A + (size_t)(m0 + (wv    )*16 + r4) * ldA + k8;
  const bf16_t* gA1 = A + (size_t)(m0 + (wv + 4)*16 + r4) * ldA + k8;
  const int la0 = (wv    ) * 512;
  const int la1 = (wv + 4) * 512;
  const bf16_t* gB0 = B + (size_t)(n0 + (wv    )*16 + r4) * ldB + k8;
  const bf16_t* gB1 = B + (size_t)(n0 + (wv + 4)*16 + r4) * ldB + k8;
  (void)BSRC;

#pragma unroll
  for (int i = 0; i < 4; ++i)
#pragma unroll
    for (int j = 0; j < 4; ++j)
      acc[i][j] = f32x4{0.f, 0.f, 0.f, 0.f};

  const int lr = lane & 15;
  const int lk = (lane >> 4) * 8;
  int aidx[4], bidx[4];
#pragma unroll
  for (int f = 0; f < 4; ++f) {
    aidx[f] = (wr*64 + f*16 + lr)*32 + lk;
    bidx[f] = (wc*64 + f*16 + lr)*32 + lk;
  }

  auto stage = [&](int bufp, int kt) {
    const int kb = kt * 32;
    gload16(gA0 + kb, &lA[bufp][la0]);
    gload16(gA1 + kb, &lA[bufp][la1]);
    gload16(gB0 + kb, &lB[bufp][lb_off0()]);
    gload16(gB1 + kb, &lB[bufp][lb_off1()]);
  };

  stage(0, 0);
  __syncthreads();
  int buf = 0;
  for (int kt = 0; kt < KT; ++kt) {
    if (kt + 1 < KT) stage(buf ^ 1, kt + 1);
    bf16x8 av[4], bvv[4];
#pragma unroll
    for (int f = 0; f < 4; ++f) av[f]  = *(const bf16x8*)&lA[buf][aidx[f]];
#pragma unroll
    for (int f = 0; f < 4; ++f) bvv[f] = *(const bf16x8*)&lB[buf][bidx[f]];
#pragma unroll
    for (int i = 0; i < 4; ++i)
#pragma unroll
      for (int j = 0; j < 4; ++j)
        acc[i][j] = __builtin_amdgcn_mfma_f32_16x16x32_bf16(av[i], bvv[j], acc[i][j], 0, 0, 0);
    __syncthreads();
    buf ^= 1;
  }
}

// ========== 128x256 conv core: grouped-lgkm single-barrier, 2 blocks/CU ==========
// C[128 rows, 256 tokens] = A * im2col(img). 72 K-tiles of BK=32. 8 waves
// (wm 2 x wn 4), wave tile 64x64, acc[4][4] (64 VGPR). LDS 48KB -> with
// <=128 VGPR (__launch_bounds__(512,4)) 2 blocks/CU co-reside: the other
// block fills this block's read-head and vmcnt/barrier tail (R12's overlap
// + R6's TLP combined).
// Per K-tile p (ONE barrier):
//   reads grp1: av0,av1,bv0..3 (6 ds_read_b128) | grp2: av2,av3 (2)
//   stage ALL of p+1 (3 gload_lds, vmcnt-only)
//   lgkm(2) -> 8 MFMA (f0,f1 x c0..3)   [grp2 + stage hide under these]
//   lgkm(0) -> 8 MFMA (f2,f3 x c0..3)
//   vmcnt(0) ; s_barrier
// RAW reads(p): buf staged during p-1, confirmed at p-1's vmcnt(0)+barrier.
// WAR stage(p+1)->buf^1: its readers retired at p-1's lgkm(0), before p-1's
// closing barrier. DS ops retire in issue order -> grouped lgkm valid; SBAR0
// after every waitcnt (rule #18).
// Swizzle (measured 0-conflict, R3-R6): writer ksX=(tid&3)^((tid>>3)&3) on
// pre-swizzled global source; reader slotS=(lane>>4)^((lane&6)>>1).
template<int STRIDE>
__device__ __forceinline__ void conv128x256g_core(
    const bf16_t* __restrict__ A, const bf16_t* __restrict__ img,
    int m0, int n0, f32x4 acc[4][4])
{
  __shared__ bf16_t ldsA[2][4096];
  __shared__ bf16_t ldsB[2][8192];
  const int tid  = threadIdx.x;           // 0..511
  const int lane = tid & 63;
  const int w    = tid >> 6;
  const int wm   = w >> 2;                // 0..1
  const int wn   = w & 3;                 // 0..3

#pragma unroll
  for (int f = 0; f < 4; ++f)
#pragma unroll
    for (int c = 0; c < 4; ++c)
      acc[f][c] = f32x4{0.f, 0.f, 0.f, 0.f};

  // ---- staging precompute (writer side, pre-swizzled source) ----
  const int srow = tid >> 2;                           // 0..127
  const int ksX  = (tid & 3) ^ ((tid >> 3) & 3);       // sigma'd k-slot
  const bf16_t* gA0 = A + (size_t)(m0 + srow) * 2304 + ksX*8;
  const int tk0 = n0 + srow, tk1 = tk0 + 128;
  int px0, px1;
  if (STRIDE == 1) { px0 = (tk0>>6)*66 + (tk0&63);       px1 = (tk1>>6)*66 + (tk1&63); }
  else             { px0 = ((tk0>>5)*2)*66 + (tk0&31)*2; px1 = ((tk1>>5)*2)*66 + (tk1&31)*2; }
  const bf16_t* gB0 = img + (size_t)px0*256 + ksX*8;
  const bf16_t* gB1 = img + (size_t)px1*256 + ksX*8;

  auto stageHalf = [&](int half, int buf) {
    gload16(gA0 + half*32, &ldsA[buf][0] + tid*8);
    const int tap = half >> 3;
    const int ky  = (tap >= 6) ? 2 : ((tap >= 3) ? 1 : 0);
    const int kx  = tap - ky*3;
    const int ps  = (ky*66 + kx)*256 + (half & 7)*32;
    bf16_t* dB = &ldsB[buf][0] + tid*8;
    gload16(gB0 + ps, dB);
    gload16(gB1 + ps, dB + 4096);
  };

  // ---- reader precompute (swizzled ds_read offsets, elements) ----
  const int lr    = lane & 15;
  const int slotS = (lane >> 4) ^ ((lane & 6) >> 1);
  int offA[4], offB[4];
#pragma unroll
  for (int f = 0; f < 4; ++f) offA[f] = (wm*64 + f*16 + lr)*32 + slotS*8;
#pragma unroll
  for (int c = 0; c < 4; ++c) offB[c] = (wn*64 + c*16 + lr)*32 + slotS*8;

  // ---- prologue ----
  stageHalf(0, 0);
  SBAR0;
  asm volatile("s_waitcnt vmcnt(0)" ::: "memory");
  SBAR0;
  __builtin_amdgcn_s_barrier();
  SBAR0;

  for (int p = 0; p < 72; ++p) {
    const int buf = p & 1;
    const bf16_t* pA = &ldsA[buf][0];
    const bf16_t* pB = &ldsB[buf][0];
    bf16x8 av[4], bv[4];
    // grp1: av0, av1, bv0..3 (6 reads)
    av[0] = *(const bf16x8*)(pA + offA[0]);
    av[1] = *(const bf16x8*)(pA + offA[1]);
#pragma unroll
    for (int c = 0; c < 4; ++c) bv[c] = *(const bf16x8*)(pB + offB[c]);
    SBAR0;
    // grp2: av2, av3 (2 reads)
    av[2] = *(const bf16x8*)(pA + offA[2]);
    av[3] = *(const bf16x8*)(pA + offA[3]);
    SBAR0;
    // stage next (vmcnt-only)
    if (p + 1 < 72) stageHalf(p + 1, buf ^ 1);
    SBAR0;
    __builtin_amdgcn_s_setprio(1);
    asm volatile("s_waitcnt lgkmcnt(2)" ::: "memory");
    SBAR0;
#pragma unroll
    for (int f = 0; f < 2; ++f)
#pragma unroll
      for (int c = 0; c < 4; ++c)
        acc[f][c] = __builtin_amdgcn_mfma_f32_16x16x32_bf16(av[f], bv[c], acc[f][c], 0, 0, 0);
    SBAR0;
    asm volatile("s_waitcnt lgkmcnt(0)" ::: "memory");
    SBAR0;
#pragma unroll
    for (int f = 2; f < 4; ++f)
#pragma unroll
      for (int c = 0; c < 4; ++c)
        acc[f][c] = __builtin_amdgcn_mfma_f32_16x16x32_bf16(av[f], bv[c], acc[f][c], 0, 0, 0);
    __builtin_amdgcn_s_setprio(0);
    SBAR0;
    asm volatile("s_waitcnt vmcnt(0)" ::: "memory");
    SBAR0;
    __builtin_amdgcn_s_barrier();
    SBAR0;
  }
}

// ---------------- QK convs (stride 2), grouped core, 2 blocks/CU ----------------
// XCD-clustered 1D grid: n%8 = b -> XCD owns one batch's images.
__global__ __launch_bounds__(512, 4) void k_conv_qk8(const bf16_t* __restrict__ wqs,
    const bf16_t* __restrict__ xp, const bf16_t* __restrict__ yp,
    bf16_t* __restrict__ qk, const float* __restrict__ shq)
{
  const int n  = blockIdx.x;
  const int b  = n & 7;
  const int r1 = n >> 3;
  const int ci = r1 & 3;
  const int r2 = r1 >> 2;
  const int nt = r2 & 3;         // 0..3
  const int mt = r2 >> 2;        // 0..7
  const int m0 = mt*128, n0 = nt*256;
  const bf16_t* A = wqs + (size_t)ci * 1024 * 2304;
  const bf16_t* img = (((ci == 0) | (ci == 3)) ? xp : yp) + (size_t)b*4356*256;
  f32x4 acc[4][4];
  conv128x256g_core<2>(A, img, m0, n0, acc);

  bf16_t* out = qk + (size_t)(ci*8 + b) * 1024 * 1024;
  const float* sh = shq + ci*1024;
  const int lane = threadIdx.x & 63, w = threadIdx.x >> 6;
  const int wm = w >> 2, wn = w & 3;
#pragma unroll
  for (int f = 0; f < 4; ++f) {
    const int row0 = m0 + wm*64 + f*16 + ((lane >> 4) << 2);
    const f32x4 s4 = *(const f32x4*)&sh[row0];
#pragma unroll
    for (int c = 0; c < 4; ++c) {
      const int col = n0 + wn*64 + c*16 + (lane & 15);
#pragma unroll
      for (int r = 0; r < 4; ++r)
        out[(size_t)(row0 + r)*1024 + col] = (bf16_t)(acc[f][c][r] + s4[r]);
    }
  }
}

// ---------------- output convs (stride 1, per-batch weights), 2 blocks/CU ----------------
__global__ __launch_bounds__(512, 4) void k_conv_out8(const bf16_t* __restrict__ weff,
    const bf16_t* __restrict__ xp, const bf16_t* __restrict__ yp,
    const float* __restrict__ bias, float* __restrict__ dout)
{
  const int n  = blockIdx.x;
  const int b  = n & 7;
  const int r1 = n >> 3;
  const int br = r1 & 1;
  const int r2 = r1 >> 1;
  const int nt = r2 & 15;        // 0..15
  const int mt = r2 >> 4;        // 0..1
  const int m0 = mt*128, n0 = nt*256;
  const bf16_t* A = weff + (size_t)(br*8 + b)*589824;
  const bf16_t* img = ((br == 0) ? yp : xp) + (size_t)b*4356*256;   // o1 from y, o2 from x
  f32x4 acc[4][4];
  conv128x256g_core<1>(A, img, m0, n0, acc);

  float* outp = dout + (size_t)br*8388608 + (size_t)b*1048576;
  const float* bp = bias + (size_t)(br*8 + b)*256;
  const int lane = threadIdx.x & 63, w = threadIdx.x >> 6;
  const int wm = w >> 2, wn = w & 3;
#pragma unroll
  for (int f = 0; f < 4; ++f) {
    const int e0 = m0 + wm*64 + f*16 + ((lane >> 4) << 2);
    const f32x4 bv4 = *(const f32x4*)&bp[e0];
#pragma unroll
    for (int c = 0; c < 4; ++c) {
      const int tok = n0 + wn*64 + c*16 + (lane & 15);
      f32x4 v = acc[f][c] + bv4;
      *(f32x4*)&outp[(size_t)tok*256 + e0] = v;
    }
  }
}

// ---------------- pack + pad (vectorized): [B,4096,256] f32 -> [B,66,66,256] bf16 ----------------
__global__ __launch_bounds__(256) void k_pack(const float* __restrict__ x, const float* __restrict__ y,
                                              bf16_t* __restrict__ xp, bf16_t* __restrict__ yp)
{
  const int t   = threadIdx.x;
  const int pix = blockIdx.x*4 + (t >> 6);   // 0..4355
  const int c4  = (t & 63) * 4;
  const int b   = blockIdx.y;
  const int im  = blockIdx.z;
  const int i = pix / 66, j = pix - i*66;
  const float* src = im ? y : x;
  bf16_t* dst = im ? yp : xp;
  float4 v = make_float4(0.f, 0.f, 0.f, 0.f);
  if (i >= 1 && i <= 64 && j >= 1 && j <= 64)
    v = *(const float4*)&src[((size_t)b*4096 + (size_t)(i-1)*64 + (j-1))*256 + c4];
  bf16_t o4[4] = {(bf16_t)v.x, (bf16_t)v.y, (bf16_t)v.z, (bf16_t)v.w};
  *(uint64_t*)&dst[((size_t)b*4356 + pix)*256 + c4] = *(const uint64_t*)o4;
}

// ---------------- weight prep: QK convs (0..3) ----------------
__global__ __launch_bounds__(256) void k_prep_wq(const float* __restrict__ wcv,
    const float* __restrict__ g, const float* __restrict__ be,
    const float* __restrict__ mu, const float* __restrict__ va,
    bf16_t* __restrict__ wqs, float* __restrict__ shq)
{
  const int blk = blockIdx.x;          // ci*1024 + hd
  __shared__ float lw[2304];
  const float* src = wcv + (size_t)blk * 2304;
  for (int t = threadIdx.x; t < 2304; t += 256) lw[t] = src[t];
  const float sc = g[blk] * rsqrtf(va[blk] + EPSBN);
  if (threadIdx.x == 0) shq[blk] = be[blk] - mu[blk]*sc;
  __syncthreads();
  bf16_t* dst = wqs + (size_t)blk * 2304;
  for (int t = threadIdx.x; t < 2304; t += 256) {
    const int tap = t >> 8, c = t & 255;
    dst[t] = (bf16_t)(lw[c*9 + tap] * sc);
  }
}

// ---------------- weight prep: V convs transposed [br][k'][hd] ----------------
__global__ __launch_bounds__(256) void k_prep_wv(const float* __restrict__ wcv,
    const float* __restrict__ g, const float* __restrict__ va,
    bf16_t* __restrict__ wvT)
{
  const int cch = blockIdx.x;                 // c0 = cch*8
  const int h = blockIdx.y >> 2, dc = blockIdx.y & 3;  // d0 = dc*64
  const int br = blockIdx.z;
  __shared__ float lw[64][72];
  __shared__ float lsc[64];
  const int ci = 4 + br;
  const int c0 = cch*8, d0 = dc*64;
  for (int e = threadIdx.x; e < 64*72; e += 256) {
    const int dd = e / 72, q = e - dd*72;
    lw[dd][q] = wcv[(size_t)(ci*1024 + h*256 + d0 + dd)*2304 + c0*9 + q];
  }
  if (threadIdx.x < 64) {
    const int bnIdx = ci*1024 + h*256 + d0 + threadIdx.x;
    lsc[threadIdx.x] = g[bnIdx] * rsqrtf(va[bnIdx] + EPSBN);
  }
  __syncthreads();
  for (int e = threadIdx.x; e < 72*64; e += 256) {
    const int kq = e >> 6, dd = e & 63;
    const int cc = kq / 9, tap = kq - cc*9;
    const int kp = tap*256 + c0 + cc;
    wvT[(size_t)br*2359296 + (size_t)kp*1024 + h*256 + d0 + dd] =
        (bf16_t)(lw[dd][cc*9 + tap] * lsc[dd]);
  }
}

// ---------------- small prep: w_out -> bf16, shiftV ----------------
__global__ __launch_bounds__(256) void k_small(const float* __restrict__ w1, const float* __restrict__ w2,
    const float* __restrict__ g, const float* __restrict__ be,
    const float* __restrict__ mu, const float* __restrict__ va,
    bf16_t* __restrict__ w1b, bf16_t* __restrict__ w2b, float* __restrict__ shv)
{
  const int idx = blockIdx.x*256 + threadIdx.x;
  if (idx < 65536) {
    w1b[idx] = (bf16_t)w1[idx];
  } else if (idx < 131072) {
    w2b[idx - 65536] = (bf16_t)w2[idx - 65536];
  } else if (idx < 133120) {
    const int t = idx - 131072;           // br*1024 + hd
    const int bnIdx = 4096 + t;           // (4+br)*1024 + hd
    const float sc = g[bnIdx] * rsqrtf(va[bnIdx] + EPSBN);
    shv[t] = be[bnIdx] - mu[bnIdx]*sc;
  }
}

// ---------------- score GEMM: s = Q K^T over tokens ----------------
__global__ __launch_bounds__(256) void k_gemm_s(const bf16_t* __restrict__ qk, float* __restrict__ sb)
{
  const int bx = blockIdx.x, by = blockIdx.y, br = blockIdx.z;
  const int mt = bx >> 1, nt = bx & 1;
  const int b = by >> 2, h = by & 3;
  const int ai = (br == 0) ? 1 : 0;   // Q2 / Q1
  const int bi = (br == 0) ? 2 : 3;   // K1 / K2
  const bf16_t* A  = qk + ((size_t)(ai*8 + b)*1024 + h*256) * 1024;
  const bf16_t* Bp = qk + ((size_t)(bi*8 + b)*1024 + h*256) * 1024;
  f32x4 acc[4][4];
  gemm_core<0>(A, 1024, Bp, 1024, mt*128, nt*128, 32, acc);

  float* out = sb + ((size_t)(br*8 + b)*4 + h) * 65536;
  const int lane = threadIdx.x & 63, wv = threadIdx.x >> 6;
  const int wr = wv >> 1, wc = wv & 1;
#pragma unroll
  for (int i = 0; i < 4; ++i) {
    const int row0 = mt*128 + wr*64 + i*16 + ((lane >> 4) << 2);
#pragma unroll
    for (int j = 0; j < 4; ++j) {
      const int col = nt*128 + wc*64 + j*16 + (lane & 15);
#pragma unroll
      for (int r = 0; r < 4; ++r)
        out[(size_t)(row0 + r)*256 + col] = acc[i][j][r];
    }
  }
}

// ---------------- softmax over d, write p^T (x0.25 folded) ----------------
__global__ __launch_bounds__(256) void k_softmax(const float* __restrict__ sb, bf16_t* __restrict__ pt)
{
  const int cc = blockIdx.x;     // 32-row chunk
  const int bh = blockIdx.y;     // b*4 + h
  const int br = blockIdx.z;
  const size_t base = ((size_t)br*32 + bh) * 65536;
  __shared__ bf16_t lp[32][256];
  const int tid = threadIdx.x, lane = tid & 63, wv = tid >> 6;
  for (int r = 0; r < 8; ++r) {
    const int row = wv*8 + r;
    const float* srow = sb + base + (size_t)(cc*32 + row)*256;
    f32x4 v = ((const f32x4*)srow)[lane];
    v *= 0.0625f;                               // scale_attn = 256^-0.5
    float m = fmaxf(fmaxf(v[0], v[1]), fmaxf(v[2], v[3]));
#pragma unroll
    for (int o = 32; o; o >>= 1) m = fmaxf(m, __shfl_xor(m, o));
    const float e0 = __expf(v[0]-m), e1 = __expf(v[1]-m), e2 = __expf(v[2]-m), e3 = __expf(v[3]-m);
    float s = e0+e1+e2+e3;
#pragma unroll
    for (int o = 32; o; o >>= 1) s += __shfl_xor(s, o);
    const float inv = 0.25f / s;                // head-mean folded
    lp[row][lane*4+0] = (bf16_t)(e0*inv);
    lp[row][lane*4+1] = (bf16_t)(e1*inv);
    lp[row][lane*4+2] = (bf16_t)(e2*inv);
    lp[row][lane*4+3] = (bf16_t)(e3*inv);
  }
  __syncthreads();
  bf16_t* dst = pt + base;
  for (int it = 0; it < 32; ++it) {
    const int idx = it*256 + tid;
    const int d = idx >> 5, c = idx & 31;
    dst[(size_t)d*256 + cc*32 + c] = lp[c][d];
  }
}

// ---------------- A-GEMM: A1[e, h*256+d] = w_out @ p ----------------
__global__ __launch_bounds__(256) void k_gemm_a(const bf16_t* __restrict__ w1b, const bf16_t* __restrict__ w2b,
    const bf16_t* __restrict__ pt, bf16_t* __restrict__ a1)
{
  const int bx = blockIdx.x, by = blockIdx.y, br = blockIdx.z;
  const int mt = bx >> 1, nt = bx & 1;
  const int b = by >> 2, h = by & 3;
  const bf16_t* A  = br ? w2b : w1b;
  const bf16_t* Bp = pt + ((size_t)(br*8 + b)*4 + h) * 65536;
  f32x4 acc[4][4];
  gemm_core<0>(A, 256, Bp, 256, mt*128, nt*128, 8, acc);

  bf16_t* out = a1 + (size_t)(br*8 + b)*262144 + h*256;
  const int lane = threadIdx.x & 63, wv = threadIdx.x >> 6;
  const int wr = wv >> 1, wc = wv & 1;
#pragma unroll
  for (int i = 0; i < 4; ++i) {
    const int row0 = mt*128 + wr*64 + i*16 + ((lane >> 4) << 2);
#pragma unroll
    for (int j = 0; j < 4; ++j) {
      const int col = nt*128 + wc*64 + j*16 + (lane & 15);
#pragma unroll
      for (int r = 0; r < 4; ++r)
        out[(size_t)(row0 + r)*1024 + col] = (bf16_t)acc[i][j][r];
    }
  }
}

// ---------------- bias: sum_hd A1[e,hd] * shiftV[hd] ----------------
__global__ __launch_bounds__(256) void k_bias(const bf16_t* __restrict__ a1,
    const float* __restrict__ shv, float* __restrict__ bias)
{
  const int wv = threadIdx.x >> 6, lane = threadIdx.x & 63;
  const int e = blockIdx.x*4 + wv;
  const int b = blockIdx.y, br = blockIdx.z;
  const bf16_t* row = a1 + ((size_t)(br*8 + b)*256 + e)*1024;
  const float* sv = shv + br*1024;
  float acc = 0.f;
#pragma unroll
  for (int t = 0; t < 16; ++t) {
    const int idx = t*64 + lane;
    acc += (float)row[idx] * sv[idx];
  }
#pragma unroll
  for (int o = 32; o; o >>= 1) acc += __shfl_xor(acc, o);
  if (lane == 0) bias[(size_t)(br*8 + b)*256 + e] = acc;
}

// ---------------- Weff GEMM: Weff = A1 @ WvS ----------------
__global__ __launch_bounds__(256) void k_gemm_weff(const bf16_t* __restrict__ a1,
    const bf16_t* __restrict__ wvT, bf16_t* __restrict__ weff)
{
  const int bx = blockIdx.x, b = blockIdx.y, br = blockIdx.z;
  const int mt = bx / 18, nt = bx - mt*18;
  const bf16_t* A  = a1 + (size_t)(br*8 + b)*262144;
  const bf16_t* Bp = wvT + (size_t)br*2359296;
  f32x4 acc[4][4];
  gemm_core<0>(A, 1024, Bp, 1024, mt*128, nt*128, 32, acc);

  bf16_t* out = weff + (size_t)(br*8 + b)*589824;
  const int lane = threadIdx.x & 63, wv = threadIdx.x >> 6;
  const int wr = wv >> 1, wc = wv & 1;
#pragma unroll
  for (int i = 0; i < 4; ++i) {
    const int row0 = mt*128 + wr*64 + i*16 + ((lane >> 4) << 2);
#pragma unroll
    for (int j = 0; j < 4; ++j) {
      const int col = nt*128 + wc*64 + j*16 + (lane & 15);
#pragma unroll
      for (int r = 0; r < 4; ++r)
        out[(size_t)(row0 + r)*2304 + col] = (bf16_t)acc[i][j][r];
    }
  }
}

// ---------------- host ----------------
extern "C" void kernel_launch(void* const* d_in, const int* in_sizes, int n_in,
                              void* d_out, int out_size, void* d_ws, size_t ws_size,
                              hipStream_t stream)
{
  (void)in_sizes; (void)n_in; (void)out_size;
  const float* x   = (const float*)d_in[0];
  const float* y   = (const float*)d_in[1];
  const float* wcv = (const float*)d_in[2];
  const float* bg  = (const float*)d_in[3];
  const float* bb  = (const float*)d_in[4];
  const float* bm  = (const float*)d_in[5];
  const float* bvv = (const float*)d_in[6];
  const float* w1  = (const float*)d_in[7];
  const float* w2  = (const float*)d_in[8];
  float* out = (float*)d_out;
  char* ws = (char*)d_ws;
  if (ws_size < WS_NEED) return;

  bf16_t* xp   = (bf16_t*)(ws + OFF_XP);
  bf16_t* yp   = (bf16_t*)(ws + OFF_YP);
  bf16_t* wqs  = (bf16_t*)(ws + OFF_WQS);
  bf16_t* wvT  = (bf16_t*)(ws + OFF_WVT);
  bf16_t* w1b  = (bf16_t*)(ws + OFF_W1B);
  bf16_t* w2b  = (bf16_t*)(ws + OFF_W2B);
  float*  shq  = (float*)(ws + OFF_SHQ);
  float*  shv  = (float*)(ws + OFF_SHV);
  bf16_t* qk   = (bf16_t*)(ws + OFF_QK);
  float*  sb   = (float*)(ws + OFF_S);
  bf16_t* pt   = (bf16_t*)(ws + OFF_PT);
  bf16_t* a1   = (bf16_t*)(ws + OFF_A1);
  bf16_t* weff = (bf16_t*)(ws + OFF_WEFF);
  float*  bias = (float*)(ws + OFF_BIAS);

  k_pack     <<<dim3(1089, 8, 2), 256, 0, stream>>>(x, y, xp, yp);
  k_prep_wq  <<<dim3(4096), 256, 0, stream>>>(wcv, bg, bb, bm, bvv, wqs, shq);
  k_prep_wv  <<<dim3(32, 16, 2), 256, 0, stream>>>(wcv, bg, bvv, wvT);
  k_small    <<<dim3(520), 256, 0, stream>>>(w1, w2, bg, bb, bm, bvv, w1b, w2b, shv);
  k_conv_qk8 <<<dim3(1024), 512, 0, stream>>>(wqs, xp, yp, qk, shq);
  k_gemm_s   <<<dim3(4, 32, 2), 256, 0, stream>>>(qk, sb);
  k_softmax  <<<dim3(8, 32, 2), 256, 0, stream>>>(sb, pt);
  k_gemm_a   <<<dim3(4, 32, 2), 256, 0, stream>>>(w1b, w2b, pt, a1);
  k_bias     <<<dim3(64, 8, 2), 256, 0, stream>>>(a1, shv, bias);
  k_gemm_weff<<<dim3(36, 8, 2), 256, 0, stream>>>(a1, wvT, weff);
  k_conv_out8<<<dim3(512), 512, 0, stream>>>(weff, xp, yp, bias, out);
}

// Round 15
// 328.072 us; speedup vs baseline: 1.1169x; 1.1169x over previous
//
#include <hip/hip_runtime.h>
#include <stdint.h>

typedef __bf16 bf16_t;
typedef __bf16 bf16x8 __attribute__((ext_vector_type(8)));
typedef float f32x4 __attribute__((ext_vector_type(4)));

#define EPSBN 1e-5f

// ---------------- workspace layout (bytes) ----------------
#define OFF_XP   ((size_t)0)
#define SZ_IMG   ((size_t)8*4356*256*2)          // padded NHWC bf16 image, 66x66
#define OFF_YP   (OFF_XP + SZ_IMG)
#define OFF_WQS  (OFF_YP + SZ_IMG)
#define SZ_WQS   ((size_t)4*1024*2304*2)         // scaled QK conv weights [conv][hd][tap*256+c]
#define OFF_WVT  (OFF_WQS + SZ_WQS)
#define SZ_WVT   ((size_t)2*2304*1024*2)         // scaled V weights transposed [br][k'][hd]
#define OFF_W1B  (OFF_WVT + SZ_WVT)
#define SZ_WO    ((size_t)65536*2)
#define OFF_W2B  (OFF_W1B + SZ_WO)
#define OFF_SHQ  (OFF_W2B + SZ_WO)
#define SZ_SHQ   ((size_t)4096*4)                // BN shift for convs 0..3
#define OFF_SHV  (OFF_SHQ + SZ_SHQ)
#define SZ_SHV   ((size_t)2048*4)                // BN shift for convs 4,5
#define OFF_QK   (OFF_SHV + SZ_SHV)
#define SZ_QK    ((size_t)4*8*1024*1024*2)       // Q1,Q2,K1,K2: [conv][b][hd][tok] bf16
#define OFF_S    (OFF_QK + SZ_QK)
#define SZ_S     ((size_t)2*8*4*65536*4)         // scores f32 [br][b][h][c][d]
#define OFF_PT   (OFF_S + SZ_S)
#define SZ_PT    ((size_t)2*8*4*65536*2)         // p^T bf16 [br][b][h][d][c]  (x0.25, /l folded)
#define OFF_A1   (OFF_PT + SZ_PT)
#define SZ_A1    ((size_t)2*8*256*1024*2)        // A1 bf16 [br][b][e][hd]
#define OFF_WEFF (OFF_A1 + SZ_A1)
#define SZ_WEFF  ((size_t)2*8*256*2304*2)        // Weff bf16 [br][b][e][k']
#define OFF_BIAS (OFF_WEFF + SZ_WEFF)
#define SZ_BIAS  ((size_t)2*8*256*4)
#define WS_NEED  (OFF_BIAS + SZ_BIAS)

__device__ __forceinline__ void gload16(const bf16_t* g, bf16_t* l) {
  __builtin_amdgcn_global_load_lds(
      (const __attribute__((address_space(1))) void*)g,
      (__attribute__((address_space(3))) void*)l,
      16, 0, 0);
}

// staging LDS offsets for the B tile (wave wv owns chunks {wv, wv+4})
__device__ __forceinline__ int lb_off0() { return ((threadIdx.x >> 6)    ) * 512; }
__device__ __forceinline__ int lb_off1() { return ((threadIdx.x >> 6) + 4) * 512; }

#define SBAR0 __builtin_amdgcn_sched_barrier(0)

// ---------------- old GEMM core: 128x128 tile, BK=32, 4 waves (small GEMMs) ----------------
template<int BSRC>
__device__ __forceinline__ void gemm_core(
    const bf16_t* __restrict__ A, int ldA,
    const bf16_t* __restrict__ B, int ldB,
    int m0, int n0, int KT, f32x4 acc[4][4])
{
  __shared__ bf16_t lA[2][4096];
  __shared__ bf16_t lB[2][4096];
  const int tid  = threadIdx.x;
  const int lane = tid & 63;
  const int wv   = tid >> 6;
  const int wr   = wv >> 1, wc = wv & 1;
  const int r4   = lane >> 2;       // 0..15
  const int k8   = (lane & 3) * 8;  // 0,8,16,24

  const bf16_t* gA0 = A + (size_t)(m0 + (wv    )*16 + r4) * ldA + k8;
  const bf16_t* gA1 = A + (size_t)(m0 + (wv + 4)*16 + r4) * ldA + k8;
  const int la0 = (wv    ) * 512;
  const int la1 = (wv + 4) * 512;
  const bf16_t* gB0 = B + (size_t)(n0 + (wv    )*16 + r4) * ldB + k8;
  const bf16_t* gB1 = B + (size_t)(n0 + (wv + 4)*16 + r4) * ldB + k8;
  (void)BSRC;

#pragma unroll
  for (int i = 0; i < 4; ++i)
#pragma unroll
    for (int j = 0; j < 4; ++j)
      acc[i][j] = f32x4{0.f, 0.f, 0.f, 0.f};

  const int lr = lane & 15;
  const int lk = (lane >> 4) * 8;
  int aidx[4], bidx[4];
#pragma unroll
  for (int f = 0; f < 4; ++f) {
    aidx[f] = (wr*64 + f*16 + lr)*32 + lk;
    bidx[f] = (wc*64 + f*16 + lr)*32 + lk;
  }

  auto stage = [&](int bufp, int kt) {
    const int kb = kt * 32;
    gload16(gA0 + kb, &lA[bufp][la0]);
    gload16(gA1 + kb, &lA[bufp][la1]);
    gload16(gB0 + kb, &lB[bufp][lb_off0()]);
    gload16(gB1 + kb, &lB[bufp][lb_off1()]);
  };

  stage(0, 0);
  __syncthreads();
  int buf = 0;
  for (int kt = 0; kt < KT; ++kt) {
    if (kt + 1 < KT) stage(buf ^ 1, kt + 1);
    bf16x8 av[4], bvv[4];
#pragma unroll
    for (int f = 0; f < 4; ++f) av[f]  = *(const bf16x8*)&lA[buf][aidx[f]];
#pragma unroll
    for (int f = 0; f < 4; ++f) bvv[f] = *(const bf16x8*)&lB[buf][bidx[f]];
#pragma unroll
    for (int i = 0; i < 4; ++i)
#pragma unroll
      for (int j = 0; j < 4; ++j)
        acc[i][j] = __builtin_amdgcn_mfma_f32_16x16x32_bf16(av[i], bvv[j], acc[i][j], 0, 0, 0);
    __syncthreads();
    buf ^= 1;
  }
}

// ================= 256x256 conv core: single-barrier tile, 8-step lgkm ladder =================
// C = A[256,K=2304] * im2col(img)[K,256]. 36 K-tiles of BK=64, 8 waves.
// LDS: lA[2buf][2half][128x64] + lB same = 128 KB. 1 block/CU.
// Identical sync structure to R12 (proven): reads issued in pinned order
// bvs0(4)|avl(8)|bvs1(4)|avh(8), stage ALL of T+1 (8 gloads, vmcnt-only),
// MFMAs gated by counted lgkm, vmcnt(0), ONE barrier per tile.
// Fine lgkm ladder (all thresholds <=15, 4-bit field!) so the MFMA pipe is
// fed as reads land (reads 12 cyc vs MFMA 4.85 -> rate-matched):
//   lgkm(15)->acc[0..1][0..1]  14->acc[2]  12->acc[3]
//   lgkm(8) ->acc[0..3][2..3]
//   lgkm(6) ->acc[4]  4->acc[5]  2->acc[6]
//   lgkm(0) ->acc[7] + acc[4..7][2..3]
// Gating audit: acc[0] needs reads 1-6, acc[1] needs 1-4,7-8 -> lgkm(15)
// (first 9 done) covers both. acc[2] needs 9-10 -> lgkm(14). acc[3] needs
// 11-12 -> lgkm(12). acc[i][2..3] need bvs1 = 13-16 -> lgkm(8). avh reads
// 17-24 -> 6/4/2/0. Monotone on in-order DS queue.
// RAW/WAR chain unchanged from R12 (verified). Swizzle: writer thread t
// (row r=t>>3, slot s=t&7) sources global k-slot s^(r&7); reader slot sg
// at (sg^(lane&7))*8.
template<int STRIDE>
__device__ __forceinline__ void conv_m201_core(
    const bf16_t* __restrict__ A, const bf16_t* __restrict__ img,
    int m0, int n0, f32x4 acc[8][4])
{
  __shared__ bf16_t lA[2][2][8192];
  __shared__ bf16_t lB[2][2][8192];
  const int tid  = threadIdx.x;           // 0..511
  const int lane = tid & 63;
  const int w    = tid >> 6;
  const int wm   = w >> 2;                // 0..1
  const int wn   = w & 3;                 // 0..3
  const int wh   = wn >> 1;               // B half
  const int wn1  = wn & 1;

#pragma unroll
  for (int f = 0; f < 8; ++f)
#pragma unroll
    for (int c = 0; c < 4; ++c)
      acc[f][c] = f32x4{0.f, 0.f, 0.f, 0.f};

  // ---- writer precompute (pre-swizzled global source) ----
  const int srow = tid >> 3;                       // 0..63 (chunk row)
  const int swz  = ((tid & 7) ^ (srow & 7)) * 8;   // element offset in 64-k row
  const bf16_t* gAsrc = A + (size_t)(m0 + srow) * 2304 + swz;
  const bf16_t* gBsrc[4];
#pragma unroll
  for (int h = 0; h < 2; ++h)
#pragma unroll
    for (int c = 0; c < 2; ++c) {
      const int tok = n0 + h*128 + c*64 + srow;
      int px;
      if (STRIDE == 1) px = (tok >> 6)*66 + (tok & 63);
      else             px = ((tok >> 5)*2)*66 + (tok & 31)*2;
      gBsrc[h*2 + c] = img + (size_t)px*256 + swz;
    }

  auto stageA = [&](int T1, int h) {
    bf16_t* dst = &lA[T1 & 1][h][0] + tid*8;
    const bf16_t* src = gAsrc + (size_t)(h*128)*2304 + T1*64;
    gload16(src, dst);
    gload16(src + (size_t)64*2304, dst + 4096);
  };
  auto stageB = [&](int T1, int h) {
    const int tap = T1 >> 2;
    const int ky  = (tap >= 6) ? 2 : ((tap >= 3) ? 1 : 0);
    const int kx  = tap - ky*3;
    const int ps  = (ky*66 + kx)*256 + (T1 & 3)*64;
    bf16_t* dst = &lB[T1 & 1][h][0] + tid*8;
    gload16(gBsrc[h*2 + 0] + ps, dst);
    gload16(gBsrc[h*2 + 1] + ps, dst + 4096);
  };

  // ---- reader precompute (swizzled ds_read offsets, elements) ----
  const int rb  = (lane & 15) * 64;
  const int l7  = lane & 7;
  const int g4  = lane >> 4;
  int rs[2];
  rs[0] = ((    g4) ^ l7) * 8;
  rs[1] = ((4 + g4) ^ l7) * 8;

  // ---- prologue: stage ALL of K-tile 0; confirm fully ----
  stageA(0, 0); stageB(0, 0); stageA(0, 1); stageB(0, 1);
  SBAR0;
  asm volatile("s_waitcnt vmcnt(0)" ::: "memory");
  SBAR0;
  __builtin_amdgcn_s_barrier();

#define MFMA2(F, J, AV) do {                                                  \
    acc[F][J] = __builtin_amdgcn_mfma_f32_16x16x32_bf16(AV[0], bvs[(J)>>1][(J)&1][0], acc[F][J], 0, 0, 0); \
    acc[F][J] = __builtin_amdgcn_mfma_f32_16x16x32_bf16(AV[1], bvs[(J)>>1][(J)&1][1], acc[F][J], 0, 0, 0); \
  } while (0)

  for (int T = 0; T < 36; ++T) {
    const int buf = T & 1;
    const bf16_t* pa = &lA[buf][wm][0];
    const bf16_t* pb = &lB[buf][wh][0];
    bf16x8 avl[4][2], avh[4][2], bvs[2][2][2];
    const bool nt = (T + 1 < 36);

    // ---- read group 1: bvs[0] (4) ----
#pragma unroll
    for (int j = 0; j < 2; ++j)
#pragma unroll
      for (int kh = 0; kh < 2; ++kh)
        bvs[0][j][kh] = *(const bf16x8*)(pb + (wn1*4096 + j*1024 + rb + rs[kh]));
    SBAR0;
    // ---- read group 2: av_lo (8, ordered i=0..3) ----
#pragma unroll
    for (int i = 0; i < 4; ++i)
#pragma unroll
      for (int kh = 0; kh < 2; ++kh)
        avl[i][kh] = *(const bf16x8*)(pa + (i*1024 + rb + rs[kh]));
    SBAR0;
    // ---- read group 3: bvs[1] (4) ----
#pragma unroll
    for (int j = 0; j < 2; ++j)
#pragma unroll
      for (int kh = 0; kh < 2; ++kh)
        bvs[1][j][kh] = *(const bf16x8*)(pb + (wn1*4096 + (2+j)*1024 + rb + rs[kh]));
    SBAR0;
    // ---- read group 4: av_hi (8, ordered i=0..3) ----
#pragma unroll
    for (int i = 0; i < 4; ++i)
#pragma unroll
      for (int kh = 0; kh < 2; ++kh)
        avh[i][kh] = *(const bf16x8*)(pa + ((4+i)*1024 + rb + rs[kh]));
    SBAR0;
    // ---- stage ALL of T+1 (vmcnt-only) ----
    if (nt) { stageA(T+1, 0); stageB(T+1, 0); stageA(T+1, 1); stageB(T+1, 1); }
    SBAR0;

    __builtin_amdgcn_s_setprio(1);
    // ---- ladder: feed MFMA as reads land (thresholds <= 15) ----
    asm volatile("s_waitcnt lgkmcnt(15)" ::: "memory"); SBAR0;
    MFMA2(0,0,avl[0]); MFMA2(0,1,avl[0]);
    MFMA2(1,0,avl[1]); MFMA2(1,1,avl[1]);
    SBAR0;
    asm volatile("s_waitcnt lgkmcnt(14)" ::: "memory"); SBAR0;
    MFMA2(2,0,avl[2]); MFMA2(2,1,avl[2]);
    SBAR0;
    asm volatile("s_waitcnt lgkmcnt(12)" ::: "memory"); SBAR0;
    MFMA2(3,0,avl[3]); MFMA2(3,1,avl[3]);
    SBAR0;
    asm volatile("s_waitcnt lgkmcnt(8)" ::: "memory"); SBAR0;
#pragma unroll
    for (int i = 0; i < 4; ++i) { MFMA2(i,2,avl[i]); MFMA2(i,3,avl[i]); }
    SBAR0;
    asm volatile("s_waitcnt lgkmcnt(6)" ::: "memory"); SBAR0;
    MFMA2(4,0,avh[0]); MFMA2(4,1,avh[0]);
    SBAR0;
    asm volatile("s_waitcnt lgkmcnt(4)" ::: "memory"); SBAR0;
    MFMA2(5,0,avh[1]); MFMA2(5,1,avh[1]);
    SBAR0;
    asm volatile("s_waitcnt lgkmcnt(2)" ::: "memory"); SBAR0;
    MFMA2(6,0,avh[2]); MFMA2(6,1,avh[2]);
    SBAR0;
    asm volatile("s_waitcnt lgkmcnt(0)" ::: "memory"); SBAR0;
    MFMA2(7,0,avh[3]); MFMA2(7,1,avh[3]);
#pragma unroll
    for (int i = 0; i < 4; ++i) { MFMA2(4+i,2,avh[i]); MFMA2(4+i,3,avh[i]); }
    __builtin_amdgcn_s_setprio(0);
    SBAR0;
    // ---- close tile: stage(T+1) certainly landed; sync ----
    asm volatile("s_waitcnt vmcnt(0)" ::: "memory");
    SBAR0;
    __builtin_amdgcn_s_barrier();
  }
#undef MFMA2
}

// ---------------- QK convs (stride 2) ----------------
// bid%8 = batch (XCD owns one batch's images; lowest-FETCH config, R6).
__global__ __launch_bounds__(512, 1) void k_conv_qk7(const bf16_t* __restrict__ wqs,
    const bf16_t* __restrict__ xp, const bf16_t* __restrict__ yp,
    bf16_t* __restrict__ qk, const float* __restrict__ shq)
{
  const int n  = blockIdx.x;
  const int b  = n & 7;
  const int r1 = n >> 3;         // 0..63
  const int ci = r1 & 3;
  const int r2 = r1 >> 2;        // 0..15
  const int nt = r2 & 3;
  const int mt = r2 >> 2;        // 0..3
  const int m0 = mt*256, n0 = nt*256;
  const bf16_t* A = wqs + (size_t)ci * 1024 * 2304;
  const bf16_t* img = (((ci == 0) | (ci == 3)) ? xp : yp) + (size_t)b*4356*256;
  f32x4 acc[8][4];
  conv_m201_core<2>(A, img, m0, n0, acc);

  bf16_t* out = qk + (size_t)(ci*8 + b) * 1024 * 1024;
  const float* sh = shq + ci*1024;
  const int lane = threadIdx.x & 63, w = threadIdx.x >> 6;
  const int wm = w >> 2, wn = w & 3;
#pragma unroll
  for (int f = 0; f < 8; ++f) {
    const int row0 = m0 + wm*128 + f*16 + ((lane >> 4) << 2);
    const f32x4 s4 = *(const f32x4*)&sh[row0];
#pragma unroll
    for (int c = 0; c < 4; ++c) {
      const int col = n0 + wn*64 + c*16 + (lane & 15);
#pragma unroll
      for (int r = 0; r < 4; ++r)
        out[(size_t)(row0 + r)*1024 + col] = (bf16_t)(acc[f][c][r] + s4[r]);
    }
  }
}

// ---------------- output convs (stride 1, per-batch weights) ----------------
__global__ __launch_bounds__(512, 1) void k_conv_out7(const bf16_t* __restrict__ weff,
    const bf16_t* __restrict__ xp, const bf16_t* __restrict__ yp,
    const float* __restrict__ bias, float* __restrict__ dout)
{
  const int n  = blockIdx.x;
  const int b  = n & 7;
  const int r1 = n >> 3;         // 0..31
  const int br = r1 & 1;
  const int nt = r1 >> 1;        // 0..15
  const int n0 = nt*256;
  const bf16_t* A = weff + (size_t)(br*8 + b)*589824;
  const bf16_t* img = ((br == 0) ? yp : xp) + (size_t)b*4356*256;   // o1 from y, o2 from x
  f32x4 acc[8][4];
  conv_m201_core<1>(A, img, 0, n0, acc);

  float* outp = dout + (size_t)br*8388608 + (size_t)b*1048576;
  const float* bp = bias + (size_t)(br*8 + b)*256;
  const int lane = threadIdx.x & 63, w = threadIdx.x >> 6;
  const int wm = w >> 2, wn = w & 3;
#pragma unroll
  for (int f = 0; f < 8; ++f) {
    const int e0 = wm*128 + f*16 + ((lane >> 4) << 2);
    const f32x4 bv4 = *(const f32x4*)&bp[e0];
#pragma unroll
    for (int c = 0; c < 4; ++c) {
      const int tok = n0 + wn*64 + c*16 + (lane & 15);
      f32x4 v = acc[f][c] + bv4;
      *(f32x4*)&outp[(size_t)tok*256 + e0] = v;
    }
  }
}

// ---------------- pack + pad (vectorized): [B,4096,256] f32 -> [B,66,66,256] bf16 ----------------
__global__ __launch_bounds__(256) void k_pack(const float* __restrict__ x, const float* __restrict__ y,
                                              bf16_t* __restrict__ xp, bf16_t* __restrict__ yp)
{
  const int t   = threadIdx.x;
  const int pix = blockIdx.x*4 + (t >> 6);   // 0..4355
  const int c4  = (t & 63) * 4;
  const int b   = blockIdx.y;
  const int im  = blockIdx.z;
  const int i = pix / 66, j = pix - i*66;
  const float* src = im ? y : x;
  bf16_t* dst = im ? yp : xp;
  float4 v = make_float4(0.f, 0.f, 0.f, 0.f);
  if (i >= 1 && i <= 64 && j >= 1 && j <= 64)
    v = *(const float4*)&src[((size_t)b*4096 + (size_t)(i-1)*64 + (j-1))*256 + c4];
  bf16_t o4[4] = {(bf16_t)v.x, (bf16_t)v.y, (bf16_t)v.z, (bf16_t)v.w};
  *(uint64_t*)&dst[((size_t)b*4356 + pix)*256 + c4] = *(const uint64_t*)o4;
}

// ---------------- weight prep: QK convs (0..3) ----------------
__global__ __launch_bounds__(256) void k_prep_wq(const float* __restrict__ wcv,
    const float* __restrict__ g, const float* __restrict__ be,
    const float* __restrict__ mu, const float* __restrict__ va,
    bf16_t* __restrict__ wqs, float* __restrict__ shq)
{
  const int blk = blockIdx.x;          // ci*1024 + hd
  __shared__ float lw[2304];
  const float* src = wcv + (size_t)blk * 2304;
  for (int t = threadIdx.x; t < 2304; t += 256) lw[t] = src[t];
  const float sc = g[blk] * rsqrtf(va[blk] + EPSBN);
  if (threadIdx.x == 0) shq[blk] = be[blk] - mu[blk]*sc;
  __syncthreads();
  bf16_t* dst = wqs + (size_t)blk * 2304;
  for (int t = threadIdx.x; t < 2304; t += 256) {
    const int tap = t >> 8, c = t & 255;
    dst[t] = (bf16_t)(lw[c*9 + tap] * sc);
  }
}

// ---------------- weight prep: V convs transposed [br][k'][hd] ----------------
__global__ __launch_bounds__(256) void k_prep_wv(const float* __restrict__ wcv,
    const float* __restrict__ g, const float* __restrict__ va,
    bf16_t* __restrict__ wvT)
{
  const int cch = blockIdx.x;                 // c0 = cch*8
  const int h = blockIdx.y >> 2, dc = blockIdx.y & 3;  // d0 = dc*64
  const int br = blockIdx.z;
  __shared__ float lw[64][72];
  __shared__ float lsc[64];
  const int ci = 4 + br;
  const int c0 = cch*8, d0 = dc*64;
  for (int e = threadIdx.x; e < 64*72; e += 256) {
    const int dd = e / 72, q = e - dd*72;
    lw[dd][q] = wcv[(size_t)(ci*1024 + h*256 + d0 + dd)*2304 + c0*9 + q];
  }
  if (threadIdx.x < 64) {
    const int bnIdx = ci*1024 + h*256 + d0 + threadIdx.x;
    lsc[threadIdx.x] = g[bnIdx] * rsqrtf(va[bnIdx] + EPSBN);
  }
  __syncthreads();
  for (int e = threadIdx.x; e < 72*64; e += 256) {
    const int kq = e >> 6, dd = e & 63;
    const int cc = kq / 9, tap = kq - cc*9;
    const int kp = tap*256 + c0 + cc;
    wvT[(size_t)br*2359296 + (size_t)kp*1024 + h*256 + d0 + dd] =
        (bf16_t)(lw[dd][cc*9 + tap] * lsc[dd]);
  }
}

// ---------------- small prep: w_out -> bf16, shiftV ----------------
__global__ __launch_bounds__(256) void k_small(const float* __restrict__ w1, const float* __restrict__ w2,
    const float* __restrict__ g, const float* __restrict__ be,
    const float* __restrict__ mu, const float* __restrict__ va,
    bf16_t* __restrict__ w1b, bf16_t* __restrict__ w2b, float* __restrict__ shv)
{
  const int idx = blockIdx.x*256 + threadIdx.x;
  if (idx < 65536) {
    w1b[idx] = (bf16_t)w1[idx];
  } else if (idx < 131072) {
    w2b[idx - 65536] = (bf16_t)w2[idx - 65536];
  } else if (idx < 133120) {
    const int t = idx - 131072;           // br*1024 + hd
    const int bnIdx = 4096 + t;           // (4+br)*1024 + hd
    const float sc = g[bnIdx] * rsqrtf(va[bnIdx] + EPSBN);
    shv[t] = be[bnIdx] - mu[bnIdx]*sc;
  }
}

// ---------------- score GEMM: s = Q K^T over tokens ----------------
__global__ __launch_bounds__(256) void k_gemm_s(const bf16_t* __restrict__ qk, float* __restrict__ sb)
{
  const int bx = blockIdx.x, by = blockIdx.y, br = blockIdx.z;
  const int mt = bx >> 1, nt = bx & 1;
  const int b = by >> 2, h = by & 3;
  const int ai = (br == 0) ? 1 : 0;   // Q2 / Q1
  const int bi = (br == 0) ? 2 : 3;   // K1 / K2
  const bf16_t* A  = qk + ((size_t)(ai*8 + b)*1024 + h*256) * 1024;
  const bf16_t* Bp = qk + ((size_t)(bi*8 + b)*1024 + h*256) * 1024;
  f32x4 acc[4][4];
  gemm_core<0>(A, 1024, Bp, 1024, mt*128, nt*128, 32, acc);

  float* out = sb + ((size_t)(br*8 + b)*4 + h) * 65536;
  const int lane = threadIdx.x & 63, wv = threadIdx.x >> 6;
  const int wr = wv >> 1, wc = wv & 1;
#pragma unroll
  for (int i = 0; i < 4; ++i) {
    const int row0 = mt*128 + wr*64 + i*16 + ((lane >> 4) << 2);
#pragma unroll
    for (int j = 0; j < 4; ++j) {
      const int col = nt*128 + wc*64 + j*16 + (lane & 15);
#pragma unroll
      for (int r = 0; r < 4; ++r)
        out[(size_t)(row0 + r)*256 + col] = acc[i][j][r];
    }
  }
}

// ---------------- softmax over d, write p^T (x0.25 folded) ----------------
__global__ __launch_bounds__(256) void k_softmax(const float* __restrict__ sb, bf16_t* __restrict__ pt)
{
  const int cc = blockIdx.x;     // 32-row chunk
  const int bh = blockIdx.y;     // b*4 + h
  const int br = blockIdx.z;
  const size_t base = ((size_t)br*32 + bh) * 65536;
  __shared__ bf16_t lp[32][256];
  const int tid = threadIdx.x, lane = tid & 63, wv = tid >> 6;
  for (int r = 0; r < 8; ++r) {
    const int row = wv*8 + r;
    const float* srow = sb + base + (size_t)(cc*32 + row)*256;
    f32x4 v = ((const f32x4*)srow)[lane];
    v *= 0.0625f;                               // scale_attn = 256^-0.5
    float m = fmaxf(fmaxf(v[0], v[1]), fmaxf(v[2], v[3]));
#pragma unroll
    for (int o = 32; o; o >>= 1) m = fmaxf(m, __shfl_xor(m, o));
    const float e0 = __expf(v[0]-m), e1 = __expf(v[1]-m), e2 = __expf(v[2]-m), e3 = __expf(v[3]-m);
    float s = e0+e1+e2+e3;
#pragma unroll
    for (int o = 32; o; o >>= 1) s += __shfl_xor(s, o);
    const float inv = 0.25f / s;                // head-mean folded
    lp[row][lane*4+0] = (bf16_t)(e0*inv);
    lp[row][lane*4+1] = (bf16_t)(e1*inv);
    lp[row][lane*4+2] = (bf16_t)(e2*inv);
    lp[row][lane*4+3] = (bf16_t)(e3*inv);
  }
  __syncthreads();
  bf16_t* dst = pt + base;
  for (int it = 0; it < 32; ++it) {
    const int idx = it*256 + tid;
    const int d = idx >> 5, c = idx & 31;
    dst[(size_t)d*256 + cc*32 + c] = lp[c][d];
  }
}

// ---------------- A-GEMM: A1[e, h*256+d] = w_out @ p ----------------
__global__ __launch_bounds__(256) void k_gemm_a(const bf16_t* __restrict__ w1b, const bf16_t* __restrict__ w2b,
    const bf16_t* __restrict__ pt, bf16_t* __restrict__ a1)
{
  const int bx = blockIdx.x, by = blockIdx.y, br = blockIdx.z;
  const int mt = bx >> 1, nt = bx & 1;
  const int b = by >> 2, h = by & 3;
  const bf16_t* A  = br ? w2b : w1b;
  const bf16_t* Bp = pt + ((size_t)(br*8 + b)*4 + h) * 65536;
  f32x4 acc[4][4];
  gemm_core<0>(A, 256, Bp, 256, mt*128, nt*128, 8, acc);

  bf16_t* out = a1 + (size_t)(br*8 + b)*262144 + h*256;
  const int lane = threadIdx.x & 63, wv = threadIdx.x >> 6;
  const int wr = wv >> 1, wc = wv & 1;
#pragma unroll
  for (int i = 0; i < 4; ++i) {
    const int row0 = mt*128 + wr*64 + i*16 + ((lane >> 4) << 2);
#pragma unroll
    for (int j = 0; j < 4; ++j) {
      const int col = nt*128 + wc*64 + j*16 + (lane & 15);
#pragma unroll
      for (int r = 0; r < 4; ++r)
        out[(size_t)(row0 + r)*1024 + col] = (bf16_t)acc[i][j][r];
    }
  }
}

// ---------------- bias: sum_hd A1[e,hd] * shiftV[hd] ----------------
__global__ __launch_bounds__(256) void k_bias(const bf16_t* __restrict__ a1,
    const float* __restrict__ shv, float* __restrict__ bias)
{
  const int wv = threadIdx.x >> 6, lane = threadIdx.x & 63;
  const int e = blockIdx.x*4 + wv;
  const int b = blockIdx.y, br = blockIdx.z;
  const bf16_t* row = a1 + ((size_t)(br*8 + b)*256 + e)*1024;
  const float* sv = shv + br*1024;
  float acc = 0.f;
#pragma unroll
  for (int t = 0; t < 16; ++t) {
    const int idx = t*64 + lane;
    acc += (float)row[idx] * sv[idx];
  }
#pragma unroll
  for (int o = 32; o; o >>= 1) acc += __shfl_xor(acc, o);
  if (lane == 0) bias[(size_t)(br*8 + b)*256 + e] = acc;
}

// ---------------- Weff GEMM: Weff = A1 @ WvS ----------------
__global__ __launch_bounds__(256) void k_gemm_weff(const bf16_t* __restrict__ a1,
    const bf16_t* __restrict__ wvT, bf16_t* __restrict__ weff)
{
  const int bx = blockIdx.x, b = blockIdx.y, br = blockIdx.z;
  const int mt = bx / 18, nt = bx - mt*18;
  const bf16_t* A  = a1 + (size_t)(br*8 + b)*262144;
  const bf16_t* Bp = wvT + (size_t)br*2359296;
  f32x4 acc[4][4];
  gemm_core<0>(A, 1024, Bp, 1024, mt*128, nt*128, 32, acc);

  bf16_t* out = weff + (size_t)(br*8 + b)*589824;
  const int lane = threadIdx.x & 63, wv = threadIdx.x >> 6;
  const int wr = wv >> 1, wc = wv & 1;
#pragma unroll
  for (int i = 0; i < 4; ++i) {
    const int row0 = mt*128 + wr*64 + i*16 + ((lane >> 4) << 2);
#pragma unroll
    for (int j = 0; j < 4; ++j) {
      const int col = nt*128 + wc*64 + j*16 + (lane & 15);
#pragma unroll
      for (int r = 0; r < 4; ++r)
        out[(size_t)(row0 + r)*2304 + col] = (bf16_t)acc[i][j][r];
    }
  }
}

// ---------------- host ----------------
extern "C" void kernel_launch(void* const* d_in, const int* in_sizes, int n_in,
                              void* d_out, int out_size, void* d_ws, size_t ws_size,
                              hipStream_t stream)
{
  (void)in_sizes; (void)n_in; (void)out_size;
  const float* x   = (const float*)d_in[0];
  const float* y   = (const float*)d_in[1];
  const float* wcv = (const float*)d_in[2];
  const float* bg  = (const float*)d_in[3];
  const float* bb  = (const float*)d_in[4];
  const float* bm  = (const float*)d_in[5];
  const float* bvv = (const float*)d_in[6];
  const float* w1  = (const float*)d_in[7];
  const float* w2  = (const float*)d_in[8];
  float* out = (float*)d_out;
  char* ws = (char*)d_ws;
  if (ws_size < WS_NEED) return;

  bf16_t* xp   = (bf16_t*)(ws + OFF_XP);
  bf16_t* yp   = (bf16_t*)(ws + OFF_YP);
  bf16_t* wqs  = (bf16_t*)(ws + OFF_WQS);
  bf16_t* wvT  = (bf16_t*)(ws + OFF_WVT);
  bf16_t* w1b  = (bf16_t*)(ws + OFF_W1B);
  bf16_t* w2b  = (bf16_t*)(ws + OFF_W2B);
  float*  shq  = (float*)(ws + OFF_SHQ);
  float*  shv  = (float*)(ws + OFF_SHV);
  bf16_t* qk   = (bf16_t*)(ws + OFF_QK);
  float*  sb   = (float*)(ws + OFF_S);
  bf16_t* pt   = (bf16_t*)(ws + OFF_PT);
  bf16_t* a1   = (bf16_t*)(ws + OFF_A1);
  bf16_t* weff = (bf16_t*)(ws + OFF_WEFF);
  float*  bias = (float*)(ws + OFF_BIAS);

  k_pack     <<<dim3(1089, 8, 2), 256, 0, stream>>>(x, y, xp, yp);
  k_prep_wq  <<<dim3(4096), 256, 0, stream>>>(wcv, bg, bb, bm, bvv, wqs, shq);
  k_prep_wv  <<<dim3(32, 16, 2), 256, 0, stream>>>(wcv, bg, bvv, wvT);
  k_small    <<<dim3(520), 256, 0, stream>>>(w1, w2, bg, bb, bm, bvv, w1b, w2b, shv);
  k_conv_qk7 <<<dim3(512), 512, 0, stream>>>(wqs, xp, yp, qk, shq);
  k_gemm_s   <<<dim3(4, 32, 2), 256, 0, stream>>>(qk, sb);
  k_softmax  <<<dim3(8, 32, 2), 256, 0, stream>>>(sb, pt);
  k_gemm_a   <<<dim3(4, 32, 2), 256, 0, stream>>>(w1b, w2b, pt, a1);
  k_bias     <<<dim3(64, 8, 2), 256, 0, stream>>>(a1, shv, bias);
  k_gemm_weff<<<dim3(36, 8, 2), 256, 0, stream>>>(a1, wvT, weff);
  k_conv_out7<<<dim3(256), 512, 0, stream>>>(weff, xp, yp, bias, out);
}

// Round 16
// 318.129 us; speedup vs baseline: 1.1518x; 1.0313x over previous
//
#include <hip/hip_runtime.h>
#include <stdint.h>

typedef __bf16 bf16_t;
typedef __bf16 bf16x8 __attribute__((ext_vector_type(8)));
typedef float f32x4 __attribute__((ext_vector_type(4)));

#define EPSBN 1e-5f

// ---------------- workspace layout (bytes) ----------------
#define OFF_XP   ((size_t)0)
#define SZ_IMG   ((size_t)8*4356*256*2)          // padded NHWC bf16 image, 66x66
#define OFF_YP   (OFF_XP + SZ_IMG)
#define OFF_WQS  (OFF_YP + SZ_IMG)
#define SZ_WQS   ((size_t)4*1024*2304*2)         // scaled QK conv weights [conv][hd][tap*256+c]
#define OFF_WVT  (OFF_WQS + SZ_WQS)
#define SZ_WVT   ((size_t)2*2304*1024*2)         // scaled V weights transposed [br][k'][hd]
#define OFF_W1B  (OFF_WVT + SZ_WVT)
#define SZ_WO    ((size_t)65536*2)
#define OFF_W2B  (OFF_W1B + SZ_WO)
#define OFF_SHQ  (OFF_W2B + SZ_WO)
#define SZ_SHQ   ((size_t)4096*4)                // BN shift for convs 0..3
#define OFF_SHV  (OFF_SHQ + SZ_SHQ)
#define SZ_SHV   ((size_t)2048*4)                // BN shift for convs 4,5
#define OFF_QK   (OFF_SHV + SZ_SHV)
#define SZ_QK    ((size_t)4*8*1024*1024*2)       // Q1,Q2,K1,K2: [conv][b][hd][tok] bf16
#define OFF_S    (OFF_QK + SZ_QK)
#define SZ_S     ((size_t)2*8*4*65536*4)         // (unused after fusion)
#define OFF_PT   (OFF_S + SZ_S)
#define SZ_PT    ((size_t)2*8*4*65536*2)         // p^T bf16 [br][b][h][d][c]  (x0.25, /l folded)
#define OFF_A1   (OFF_PT + SZ_PT)
#define SZ_A1    ((size_t)2*8*256*1024*2)        // A1 bf16 [br][b][e][hd]
#define OFF_WEFF (OFF_A1 + SZ_A1)
#define SZ_WEFF  ((size_t)2*8*256*2304*2)        // Weff bf16 [br][b][e][k']
#define OFF_BIAS (OFF_WEFF + SZ_WEFF)
#define SZ_BIAS  ((size_t)2*8*256*4)
#define WS_NEED  (OFF_BIAS + SZ_BIAS)

__device__ __forceinline__ void gload16(const bf16_t* g, bf16_t* l) {
  __builtin_amdgcn_global_load_lds(
      (const __attribute__((address_space(1))) void*)g,
      (__attribute__((address_space(3))) void*)l,
      16, 0, 0);
}

// staging LDS offsets for the B tile (wave wv owns chunks {wv, wv+4})
__device__ __forceinline__ int lb_off0() { return ((threadIdx.x >> 6)    ) * 512; }
__device__ __forceinline__ int lb_off1() { return ((threadIdx.x >> 6) + 4) * 512; }

#define SBAR0 __builtin_amdgcn_sched_barrier(0)

// ---------------- old GEMM core: 128x128 tile, BK=32, 4 waves (small GEMMs) ----------------
template<int BSRC>
__device__ __forceinline__ void gemm_core(
    const bf16_t* __restrict__ A, int ldA,
    const bf16_t* __restrict__ B, int ldB,
    int m0, int n0, int KT, f32x4 acc[4][4])
{
  __shared__ bf16_t lA[2][4096];
  __shared__ bf16_t lB[2][4096];
  const int tid  = threadIdx.x;
  const int lane = tid & 63;
  const int wv   = tid >> 6;
  const int wr   = wv >> 1, wc = wv & 1;
  const int r4   = lane >> 2;       // 0..15
  const int k8   = (lane & 3) * 8;  // 0,8,16,24

  const bf16_t* gA0 = A + (size_t)(m0 + (wv    )*16 + r4) * ldA + k8;
  const bf16_t* gA1 = A + (size_t)(m0 + (wv + 4)*16 + r4) * ldA + k8;
  const int la0 = (wv    ) * 512;
  const int la1 = (wv + 4) * 512;
  const bf16_t* gB0 = B + (size_t)(n0 + (wv    )*16 + r4) * ldB + k8;
  const bf16_t* gB1 = B + (size_t)(n0 + (wv + 4)*16 + r4) * ldB + k8;
  (void)BSRC;

#pragma unroll
  for (int i = 0; i < 4; ++i)
#pragma unroll
    for (int j = 0; j < 4; ++j)
      acc[i][j] = f32x4{0.f, 0.f, 0.f, 0.f};

  const int lr = lane & 15;
  const int lk = (lane >> 4) * 8;
  int aidx[4], bidx[4];
#pragma unroll
  for (int f = 0; f < 4; ++f) {
    aidx[f] = (wr*64 + f*16 + lr)*32 + lk;
    bidx[f] = (wc*64 + f*16 + lr)*32 + lk;
  }

  auto stage = [&](int bufp, int kt) {
    const int kb = kt * 32;
    gload16(gA0 + kb, &lA[bufp][la0]);
    gload16(gA1 + kb, &lA[bufp][la1]);
    gload16(gB0 + kb, &lB[bufp][lb_off0()]);
    gload16(gB1 + kb, &lB[bufp][lb_off1()]);
  };

  stage(0, 0);
  __syncthreads();
  int buf = 0;
  for (int kt = 0; kt < KT; ++kt) {
    if (kt + 1 < KT) stage(buf ^ 1, kt + 1);
    bf16x8 av[4], bvv[4];
#pragma unroll
    for (int f = 0; f < 4; ++f) av[f]  = *(const bf16x8*)&lA[buf][aidx[f]];
#pragma unroll
    for (int f = 0; f < 4; ++f) bvv[f] = *(const bf16x8*)&lB[buf][bidx[f]];
#pragma unroll
    for (int i = 0; i < 4; ++i)
#pragma unroll
      for (int j = 0; j < 4; ++j)
        acc[i][j] = __builtin_amdgcn_mfma_f32_16x16x32_bf16(av[i], bvv[j], acc[i][j], 0, 0, 0);
    __syncthreads();
    buf ^= 1;
  }
}

// ================= 256x256 conv core: single-barrier tile, 8-step lgkm ladder =================
// (R12/R15 proven structure; see prior-round comments for hazard audit.)
template<int STRIDE>
__device__ __forceinline__ void conv_m201_core(
    const bf16_t* __restrict__ A, const bf16_t* __restrict__ img,
    int m0, int n0, f32x4 acc[8][4])
{
  __shared__ bf16_t lA[2][2][8192];
  __shared__ bf16_t lB[2][2][8192];
  const int tid  = threadIdx.x;           // 0..511
  const int lane = tid & 63;
  const int w    = tid >> 6;
  const int wm   = w >> 2;                // 0..1
  const int wn   = w & 3;                 // 0..3
  const int wh   = wn >> 1;               // B half
  const int wn1  = wn & 1;

#pragma unroll
  for (int f = 0; f < 8; ++f)
#pragma unroll
    for (int c = 0; c < 4; ++c)
      acc[f][c] = f32x4{0.f, 0.f, 0.f, 0.f};

  const int srow = tid >> 3;                       // 0..63 (chunk row)
  const int swz  = ((tid & 7) ^ (srow & 7)) * 8;   // element offset in 64-k row
  const bf16_t* gAsrc = A + (size_t)(m0 + srow) * 2304 + swz;
  const bf16_t* gBsrc[4];
#pragma unroll
  for (int h = 0; h < 2; ++h)
#pragma unroll
    for (int c = 0; c < 2; ++c) {
      const int tok = n0 + h*128 + c*64 + srow;
      int px;
      if (STRIDE == 1) px = (tok >> 6)*66 + (tok & 63);
      else             px = ((tok >> 5)*2)*66 + (tok & 31)*2;
      gBsrc[h*2 + c] = img + (size_t)px*256 + swz;
    }

  auto stageA = [&](int T1, int h) {
    bf16_t* dst = &lA[T1 & 1][h][0] + tid*8;
    const bf16_t* src = gAsrc + (size_t)(h*128)*2304 + T1*64;
    gload16(src, dst);
    gload16(src + (size_t)64*2304, dst + 4096);
  };
  auto stageB = [&](int T1, int h) {
    const int tap = T1 >> 2;
    const int ky  = (tap >= 6) ? 2 : ((tap >= 3) ? 1 : 0);
    const int kx  = tap - ky*3;
    const int ps  = (ky*66 + kx)*256 + (T1 & 3)*64;
    bf16_t* dst = &lB[T1 & 1][h][0] + tid*8;
    gload16(gBsrc[h*2 + 0] + ps, dst);
    gload16(gBsrc[h*2 + 1] + ps, dst + 4096);
  };

  const int rb  = (lane & 15) * 64;
  const int l7  = lane & 7;
  const int g4  = lane >> 4;
  int rs[2];
  rs[0] = ((    g4) ^ l7) * 8;
  rs[1] = ((4 + g4) ^ l7) * 8;

  stageA(0, 0); stageB(0, 0); stageA(0, 1); stageB(0, 1);
  SBAR0;
  asm volatile("s_waitcnt vmcnt(0)" ::: "memory");
  SBAR0;
  __builtin_amdgcn_s_barrier();

#define MFMA2(F, J, AV) do {                                                  \
    acc[F][J] = __builtin_amdgcn_mfma_f32_16x16x32_bf16(AV[0], bvs[(J)>>1][(J)&1][0], acc[F][J], 0, 0, 0); \
    acc[F][J] = __builtin_amdgcn_mfma_f32_16x16x32_bf16(AV[1], bvs[(J)>>1][(J)&1][1], acc[F][J], 0, 0, 0); \
  } while (0)

  for (int T = 0; T < 36; ++T) {
    const int buf = T & 1;
    const bf16_t* pa = &lA[buf][wm][0];
    const bf16_t* pb = &lB[buf][wh][0];
    bf16x8 avl[4][2], avh[4][2], bvs[2][2][2];
    const bool nt = (T + 1 < 36);

#pragma unroll
    for (int j = 0; j < 2; ++j)
#pragma unroll
      for (int kh = 0; kh < 2; ++kh)
        bvs[0][j][kh] = *(const bf16x8*)(pb + (wn1*4096 + j*1024 + rb + rs[kh]));
    SBAR0;
#pragma unroll
    for (int i = 0; i < 4; ++i)
#pragma unroll
      for (int kh = 0; kh < 2; ++kh)
        avl[i][kh] = *(const bf16x8*)(pa + (i*1024 + rb + rs[kh]));
    SBAR0;
#pragma unroll
    for (int j = 0; j < 2; ++j)
#pragma unroll
      for (int kh = 0; kh < 2; ++kh)
        bvs[1][j][kh] = *(const bf16x8*)(pb + (wn1*4096 + (2+j)*1024 + rb + rs[kh]));
    SBAR0;
#pragma unroll
    for (int i = 0; i < 4; ++i)
#pragma unroll
      for (int kh = 0; kh < 2; ++kh)
        avh[i][kh] = *(const bf16x8*)(pa + ((4+i)*1024 + rb + rs[kh]));
    SBAR0;
    if (nt) { stageA(T+1, 0); stageB(T+1, 0); stageA(T+1, 1); stageB(T+1, 1); }
    SBAR0;

    __builtin_amdgcn_s_setprio(1);
    asm volatile("s_waitcnt lgkmcnt(15)" ::: "memory"); SBAR0;
    MFMA2(0,0,avl[0]); MFMA2(0,1,avl[0]);
    MFMA2(1,0,avl[1]); MFMA2(1,1,avl[1]);
    SBAR0;
    asm volatile("s_waitcnt lgkmcnt(14)" ::: "memory"); SBAR0;
    MFMA2(2,0,avl[2]); MFMA2(2,1,avl[2]);
    SBAR0;
    asm volatile("s_waitcnt lgkmcnt(12)" ::: "memory"); SBAR0;
    MFMA2(3,0,avl[3]); MFMA2(3,1,avl[3]);
    SBAR0;
    asm volatile("s_waitcnt lgkmcnt(8)" ::: "memory"); SBAR0;
#pragma unroll
    for (int i = 0; i < 4; ++i) { MFMA2(i,2,avl[i]); MFMA2(i,3,avl[i]); }
    SBAR0;
    asm volatile("s_waitcnt lgkmcnt(6)" ::: "memory"); SBAR0;
    MFMA2(4,0,avh[0]); MFMA2(4,1,avh[0]);
    SBAR0;
    asm volatile("s_waitcnt lgkmcnt(4)" ::: "memory"); SBAR0;
    MFMA2(5,0,avh[1]); MFMA2(5,1,avh[1]);
    SBAR0;
    asm volatile("s_waitcnt lgkmcnt(2)" ::: "memory"); SBAR0;
    MFMA2(6,0,avh[2]); MFMA2(6,1,avh[2]);
    SBAR0;
    asm volatile("s_waitcnt lgkmcnt(0)" ::: "memory"); SBAR0;
    MFMA2(7,0,avh[3]); MFMA2(7,1,avh[3]);
#pragma unroll
    for (int i = 0; i < 4; ++i) { MFMA2(4+i,2,avh[i]); MFMA2(4+i,3,avh[i]); }
    __builtin_amdgcn_s_setprio(0);
    SBAR0;
    asm volatile("s_waitcnt vmcnt(0)" ::: "memory");
    SBAR0;
    __builtin_amdgcn_s_barrier();
  }
#undef MFMA2
}

// ---------------- QK convs (stride 2) ----------------
__global__ __launch_bounds__(512, 1) void k_conv_qk7(const bf16_t* __restrict__ wqs,
    const bf16_t* __restrict__ xp, const bf16_t* __restrict__ yp,
    bf16_t* __restrict__ qk, const float* __restrict__ shq)
{
  const int n  = blockIdx.x;
  const int b  = n & 7;
  const int r1 = n >> 3;         // 0..63
  const int ci = r1 & 3;
  const int r2 = r1 >> 2;        // 0..15
  const int nt = r2 & 3;
  const int mt = r2 >> 2;        // 0..3
  const int m0 = mt*256, n0 = nt*256;
  const bf16_t* A = wqs + (size_t)ci * 1024 * 2304;
  const bf16_t* img = (((ci == 0) | (ci == 3)) ? xp : yp) + (size_t)b*4356*256;
  f32x4 acc[8][4];
  conv_m201_core<2>(A, img, m0, n0, acc);

  bf16_t* out = qk + (size_t)(ci*8 + b) * 1024 * 1024;
  const float* sh = shq + ci*1024;
  const int lane = threadIdx.x & 63, w = threadIdx.x >> 6;
  const int wm = w >> 2, wn = w & 3;
#pragma unroll
  for (int f = 0; f < 8; ++f) {
    const int row0 = m0 + wm*128 + f*16 + ((lane >> 4) << 2);
    const f32x4 s4 = *(const f32x4*)&sh[row0];
#pragma unroll
    for (int c = 0; c < 4; ++c) {
      const int col = n0 + wn*64 + c*16 + (lane & 15);
#pragma unroll
      for (int r = 0; r < 4; ++r)
        out[(size_t)(row0 + r)*1024 + col] = (bf16_t)(acc[f][c][r] + s4[r]);
    }
  }
}

// ---------------- output convs (stride 1, per-batch weights) ----------------
__global__ __launch_bounds__(512, 1) void k_conv_out7(const bf16_t* __restrict__ weff,
    const bf16_t* __restrict__ xp, const bf16_t* __restrict__ yp,
    const float* __restrict__ bias, float* __restrict__ dout)
{
  const int n  = blockIdx.x;
  const int b  = n & 7;
  const int r1 = n >> 3;         // 0..31
  const int br = r1 & 1;
  const int nt = r1 >> 1;        // 0..15
  const int n0 = nt*256;
  const bf16_t* A = weff + (size_t)(br*8 + b)*589824;
  const bf16_t* img = ((br == 0) ? yp : xp) + (size_t)b*4356*256;   // o1 from y, o2 from x
  f32x4 acc[8][4];
  conv_m201_core<1>(A, img, 0, n0, acc);

  float* outp = dout + (size_t)br*8388608 + (size_t)b*1048576;
  const float* bp = bias + (size_t)(br*8 + b)*256;
  const int lane = threadIdx.x & 63, w = threadIdx.x >> 6;
  const int wm = w >> 2, wn = w & 3;
#pragma unroll
  for (int f = 0; f < 8; ++f) {
    const int e0 = wm*128 + f*16 + ((lane >> 4) << 2);
    const f32x4 bv4 = *(const f32x4*)&bp[e0];
#pragma unroll
    for (int c = 0; c < 4; ++c) {
      const int tok = n0 + wn*64 + c*16 + (lane & 15);
      f32x4 v = acc[f][c] + bv4;
      *(f32x4*)&outp[(size_t)tok*256 + e0] = v;
    }
  }
}

// ================= fused QK^T + softmax + p^T write =================
// Per block: (br, b, h, mt). s-tile = [128 c rows][256 d cols], K=1024.
// 8 waves (wm 2 x wn 4), wave tile 64x64, acc[4][4]. K-tiles of 32 with
// the proven grouped-lgkm single-barrier schedule + measured-0-conflict
// swizzle. Softmax over d: j-reduce -> 16-lane shfl reduce -> LDS [4][128]
// cross-wave combine (3 barriers). p = exp((s-m)/16) * 0.25/l written as
// p^T: for frag (i,j), lane: d = wn*64+j*16+(lane&15); c0 = mt*128+wm*64+
// i*16+((lane>>4)<<2); 4 contiguous c -> one 8B store.
__global__ __launch_bounds__(512, 1) void k_sp(const bf16_t* __restrict__ qk,
                                               bf16_t* __restrict__ pt)
{
  const int mt = blockIdx.x;          // 0..1
  const int by = blockIdx.y;          // b*4 + h
  const int br = blockIdx.z;
  const int b = by >> 2, h = by & 3;
  const int ai = (br == 0) ? 1 : 0;   // Q2 / Q1
  const int bi = (br == 0) ? 2 : 3;   // K1 / K2
  const bf16_t* A = qk + ((size_t)(ai*8 + b)*1024 + h*256 + mt*128) * 1024;
  const bf16_t* B = qk + ((size_t)(bi*8 + b)*1024 + h*256) * 1024;

  __shared__ bf16_t lA[2][4096];      // 128 x 32
  __shared__ bf16_t lB[2][8192];      // 256 x 32
  __shared__ float red[4][128];

  const int tid = threadIdx.x, lane = tid & 63, w = tid >> 6;
  const int wm = w >> 2, wn = w & 3;

  f32x4 acc[4][4];
#pragma unroll
  for (int i = 0; i < 4; ++i)
#pragma unroll
    for (int j = 0; j < 4; ++j)
      acc[i][j] = f32x4{0.f, 0.f, 0.f, 0.f};

  // staging (pre-swizzled source; same family as conv cores)
  const int srow = tid >> 2;                           // 0..127
  const int ksX  = (tid & 3) ^ ((tid >> 3) & 3);
  const bf16_t* gA  = A + (size_t)srow*1024 + ksX*8;
  const bf16_t* gB0 = B + (size_t)srow*1024 + ksX*8;
  const bf16_t* gB1 = B + (size_t)(srow + 128)*1024 + ksX*8;

  auto stage = [&](int p, int buf) {
    gload16(gA  + p*32, &lA[buf][0] + tid*8);
    bf16_t* dB = &lB[buf][0] + tid*8;
    gload16(gB0 + p*32, dB);
    gload16(gB1 + p*32, dB + 4096);
  };

  // reader (swizzled)
  const int lr    = lane & 15;
  const int slotS = (lane >> 4) ^ ((lane & 6) >> 1);
  int offA[4], offB[4];
#pragma unroll
  for (int f = 0; f < 4; ++f) offA[f] = (wm*64 + f*16 + lr)*32 + slotS*8;
#pragma unroll
  for (int c = 0; c < 4; ++c) offB[c] = (wn*64 + c*16 + lr)*32 + slotS*8;

  stage(0, 0);
  SBAR0;
  asm volatile("s_waitcnt vmcnt(0)" ::: "memory");
  SBAR0;
  __builtin_amdgcn_s_barrier();
  SBAR0;

  for (int p = 0; p < 32; ++p) {
    const int buf = p & 1;
    const bf16_t* pA = &lA[buf][0];
    const bf16_t* pB = &lB[buf][0];
    bf16x8 av[4], bv[4];
    av[0] = *(const bf16x8*)(pA + offA[0]);
    av[1] = *(const bf16x8*)(pA + offA[1]);
#pragma unroll
    for (int c = 0; c < 4; ++c) bv[c] = *(const bf16x8*)(pB + offB[c]);
    SBAR0;
    av[2] = *(const bf16x8*)(pA + offA[2]);
    av[3] = *(const bf16x8*)(pA + offA[3]);
    SBAR0;
    if (p + 1 < 32) stage(p + 1, buf ^ 1);
    SBAR0;
    __builtin_amdgcn_s_setprio(1);
    asm volatile("s_waitcnt lgkmcnt(2)" ::: "memory");
    SBAR0;
#pragma unroll
    for (int f = 0; f < 2; ++f)
#pragma unroll
      for (int c = 0; c < 4; ++c)
        acc[f][c] = __builtin_amdgcn_mfma_f32_16x16x32_bf16(av[f], bv[c], acc[f][c], 0, 0, 0);
    SBAR0;
    asm volatile("s_waitcnt lgkmcnt(0)" ::: "memory");
    SBAR0;
#pragma unroll
    for (int f = 2; f < 4; ++f)
#pragma unroll
      for (int c = 0; c < 4; ++c)
        acc[f][c] = __builtin_amdgcn_mfma_f32_16x16x32_bf16(av[f], bv[c], acc[f][c], 0, 0, 0);
    __builtin_amdgcn_s_setprio(0);
    SBAR0;
    asm volatile("s_waitcnt vmcnt(0)" ::: "memory");
    SBAR0;
    __builtin_amdgcn_s_barrier();
    SBAR0;
  }

  // ---- softmax over d (scale 1/16) ----
  const int g = lane >> 4;
  const int rowb = wm*64 + (lane >> 4)*4;   // + i*16 + r

  // row max
  f32x4 mr[4];
#pragma unroll
  for (int i = 0; i < 4; ++i) {
    f32x4 m01, m23;
#pragma unroll
    for (int r = 0; r < 4; ++r) {
      m01[r] = fmaxf(acc[i][0][r], acc[i][1][r]);
      m23[r] = fmaxf(acc[i][2][r], acc[i][3][r]);
      mr[i][r] = fmaxf(m01[r], m23[r]);
    }
  }
#pragma unroll
  for (int o = 1; o < 16; o <<= 1)
#pragma unroll
    for (int i = 0; i < 4; ++i)
#pragma unroll
      for (int r = 0; r < 4; ++r)
        mr[i][r] = fmaxf(mr[i][r], __shfl_xor(mr[i][r], o));
  if ((lane & 15) == 0) {
#pragma unroll
    for (int i = 0; i < 4; ++i)
#pragma unroll
      for (int r = 0; r < 4; ++r)
        red[wn][rowb + i*16 + r] = mr[i][r];
  }
  __syncthreads();
  f32x4 mf[4];
#pragma unroll
  for (int i = 0; i < 4; ++i)
#pragma unroll
    for (int r = 0; r < 4; ++r) {
      const int row = rowb + i*16 + r;
      mf[i][r] = fmaxf(fmaxf(red[0][row], red[1][row]), fmaxf(red[2][row], red[3][row]));
    }
  __syncthreads();

  // exp + row sum
  f32x4 sr[4];
#pragma unroll
  for (int i = 0; i < 4; ++i) {
    sr[i] = f32x4{0.f, 0.f, 0.f, 0.f};
#pragma unroll
    for (int j = 0; j < 4; ++j)
#pragma unroll
      for (int r = 0; r < 4; ++r) {
        const float e = __expf((acc[i][j][r] - mf[i][r]) * 0.0625f);
        acc[i][j][r] = e;
        sr[i][r] += e;
      }
  }
#pragma unroll
  for (int o = 1; o < 16; o <<= 1)
#pragma unroll
    for (int i = 0; i < 4; ++i)
#pragma unroll
      for (int r = 0; r < 4; ++r)
        sr[i][r] += __shfl_xor(sr[i][r], o);
  if ((lane & 15) == 0) {
#pragma unroll
    for (int i = 0; i < 4; ++i)
#pragma unroll
      for (int r = 0; r < 4; ++r)
        red[wn][rowb + i*16 + r] = sr[i][r];
  }
  __syncthreads();
  f32x4 inv[4];
#pragma unroll
  for (int i = 0; i < 4; ++i)
#pragma unroll
    for (int r = 0; r < 4; ++r) {
      const int row = rowb + i*16 + r;
      inv[i][r] = 0.25f / (red[0][row] + red[1][row] + red[2][row] + red[3][row]);
    }

  // ---- write p^T (x0.25, /l folded) ----
  bf16_t* out = pt + ((size_t)(br*8 + b)*4 + h) * 65536;
#pragma unroll
  for (int i = 0; i < 4; ++i) {
    const int c0 = mt*128 + wm*64 + i*16 + (g << 2);
#pragma unroll
    for (int j = 0; j < 4; ++j) {
      const int d = wn*64 + j*16 + (lane & 15);
      bf16_t o4[4];
#pragma unroll
      for (int r = 0; r < 4; ++r) o4[r] = (bf16_t)(acc[i][j][r] * inv[i][r]);
      *(uint64_t*)&out[(size_t)d*256 + c0] = *(const uint64_t*)o4;
    }
  }
}

// ---------------- pack + pad (vectorized): [B,4096,256] f32 -> [B,66,66,256] bf16 ----------------
__global__ __launch_bounds__(256) void k_pack(const float* __restrict__ x, const float* __restrict__ y,
                                              bf16_t* __restrict__ xp, bf16_t* __restrict__ yp)
{
  const int t   = threadIdx.x;
  const int pix = blockIdx.x*4 + (t >> 6);   // 0..4355
  const int c4  = (t & 63) * 4;
  const int b   = blockIdx.y;
  const int im  = blockIdx.z;
  const int i = pix / 66, j = pix - i*66;
  const float* src = im ? y : x;
  bf16_t* dst = im ? yp : xp;
  float4 v = make_float4(0.f, 0.f, 0.f, 0.f);
  if (i >= 1 && i <= 64 && j >= 1 && j <= 64)
    v = *(const float4*)&src[((size_t)b*4096 + (size_t)(i-1)*64 + (j-1))*256 + c4];
  bf16_t o4[4] = {(bf16_t)v.x, (bf16_t)v.y, (bf16_t)v.z, (bf16_t)v.w};
  *(uint64_t*)&dst[((size_t)b*4356 + pix)*256 + c4] = *(const uint64_t*)o4;
}

// ---------------- weight prep: QK convs (0..3) ----------------
__global__ __launch_bounds__(256) void k_prep_wq(const float* __restrict__ wcv,
    const float* __restrict__ g, const float* __restrict__ be,
    const float* __restrict__ mu, const float* __restrict__ va,
    bf16_t* __restrict__ wqs, float* __restrict__ shq)
{
  const int blk = blockIdx.x;          // ci*1024 + hd
  __shared__ float lw[2304];
  const float* src = wcv + (size_t)blk * 2304;
  for (int t = threadIdx.x; t < 2304; t += 256) lw[t] = src[t];
  const float sc = g[blk] * rsqrtf(va[blk] + EPSBN);
  if (threadIdx.x == 0) shq[blk] = be[blk] - mu[blk]*sc;
  __syncthreads();
  bf16_t* dst = wqs + (size_t)blk * 2304;
  for (int t = threadIdx.x; t < 2304; t += 256) {
    const int tap = t >> 8, c = t & 255;
    dst[t] = (bf16_t)(lw[c*9 + tap] * sc);
  }
}

// ---------------- weight prep: V convs transposed [br][k'][hd] ----------------
__global__ __launch_bounds__(256) void k_prep_wv(const float* __restrict__ wcv,
    const float* __restrict__ g, const float* __restrict__ va,
    bf16_t* __restrict__ wvT)
{
  const int cch = blockIdx.x;                 // c0 = cch*8
  const int h = blockIdx.y >> 2, dc = blockIdx.y & 3;  // d0 = dc*64
  const int br = blockIdx.z;
  __shared__ float lw[64][72];
  __shared__ float lsc[64];
  const int ci = 4 + br;
  const int c0 = cch*8, d0 = dc*64;
  for (int e = threadIdx.x; e < 64*72; e += 256) {
    const int dd = e / 72, q = e - dd*72;
    lw[dd][q] = wcv[(size_t)(ci*1024 + h*256 + d0 + dd)*2304 + c0*9 + q];
  }
  if (threadIdx.x < 64) {
    const int bnIdx = ci*1024 + h*256 + d0 + threadIdx.x;
    lsc[threadIdx.x] = g[bnIdx] * rsqrtf(va[bnIdx] + EPSBN);
  }
  __syncthreads();
  for (int e = threadIdx.x; e < 72*64; e += 256) {
    const int kq = e >> 6, dd = e & 63;
    const int cc = kq / 9, tap = kq - cc*9;
    const int kp = tap*256 + c0 + cc;
    wvT[(size_t)br*2359296 + (size_t)kp*1024 + h*256 + d0 + dd] =
        (bf16_t)(lw[dd][cc*9 + tap] * lsc[dd]);
  }
}

// ---------------- small prep: w_out -> bf16, shiftV ----------------
__global__ __launch_bounds__(256) void k_small(const float* __restrict__ w1, const float* __restrict__ w2,
    const float* __restrict__ g, const float* __restrict__ be,
    const float* __restrict__ mu, const float* __restrict__ va,
    bf16_t* __restrict__ w1b, bf16_t* __restrict__ w2b, float* __restrict__ shv)
{
  const int idx = blockIdx.x*256 + threadIdx.x;
  if (idx < 65536) {
    w1b[idx] = (bf16_t)w1[idx];
  } else if (idx < 131072) {
    w2b[idx - 65536] = (bf16_t)w2[idx - 65536];
  } else if (idx < 133120) {
    const int t = idx - 131072;           // br*1024 + hd
    const int bnIdx = 4096 + t;           // (4+br)*1024 + hd
    const float sc = g[bnIdx] * rsqrtf(va[bnIdx] + EPSBN);
    shv[t] = be[bnIdx] - mu[bnIdx]*sc;
  }
}

// ---------------- A-GEMM: A1[e, h*256+d] = w_out @ p ----------------
__global__ __launch_bounds__(256) void k_gemm_a(const bf16_t* __restrict__ w1b, const bf16_t* __restrict__ w2b,
    const bf16_t* __restrict__ pt, bf16_t* __restrict__ a1)
{
  const int bx = blockIdx.x, by = blockIdx.y, br = blockIdx.z;
  const int mt = bx >> 1, nt = bx & 1;
  const int b = by >> 2, h = by & 3;
  const bf16_t* A  = br ? w2b : w1b;
  const bf16_t* Bp = pt + ((size_t)(br*8 + b)*4 + h) * 65536;
  f32x4 acc[4][4];
  gemm_core<0>(A, 256, Bp, 256, mt*128, nt*128, 8, acc);

  bf16_t* out = a1 + (size_t)(br*8 + b)*262144 + h*256;
  const int lane = threadIdx.x & 63, wv = threadIdx.x >> 6;
  const int wr = wv >> 1, wc = wv & 1;
#pragma unroll
  for (int i = 0; i < 4; ++i) {
    const int row0 = mt*128 + wr*64 + i*16 + ((lane >> 4) << 2);
#pragma unroll
    for (int j = 0; j < 4; ++j) {
      const int col = nt*128 + wc*64 + j*16 + (lane & 15);
#pragma unroll
      for (int r = 0; r < 4; ++r)
        out[(size_t)(row0 + r)*1024 + col] = (bf16_t)acc[i][j][r];
    }
  }
}

// ---------------- bias: sum_hd A1[e,hd] * shiftV[hd] ----------------
__global__ __launch_bounds__(256) void k_bias(const bf16_t* __restrict__ a1,
    const float* __restrict__ shv, float* __restrict__ bias)
{
  const int wv = threadIdx.x >> 6, lane = threadIdx.x & 63;
  const int e = blockIdx.x*4 + wv;
  const int b = blockIdx.y, br = blockIdx.z;
  const bf16_t* row = a1 + ((size_t)(br*8 + b)*256 + e)*1024;
  const float* sv = shv + br*1024;
  float acc = 0.f;
#pragma unroll
  for (int t = 0; t < 16; ++t) {
    const int idx = t*64 + lane;
    acc += (float)row[idx] * sv[idx];
  }
#pragma unroll
  for (int o = 32; o; o >>= 1) acc += __shfl_xor(acc, o);
  if (lane == 0) bias[(size_t)(br*8 + b)*256 + e] = acc;
}

// ---------------- Weff GEMM: Weff = A1 @ WvS ----------------
__global__ __launch_bounds__(256) void k_gemm_weff(const bf16_t* __restrict__ a1,
    const bf16_t* __restrict__ wvT, bf16_t* __restrict__ weff)
{
  const int bx = blockIdx.x, b = blockIdx.y, br = blockIdx.z;
  const int mt = bx / 18, nt = bx - mt*18;
  const bf16_t* A  = a1 + (size_t)(br*8 + b)*262144;
  const bf16_t* Bp = wvT + (size_t)br*2359296;
  f32x4 acc[4][4];
  gemm_core<0>(A, 1024, Bp, 1024, mt*128, nt*128, 32, acc);

  bf16_t* out = weff + (size_t)(br*8 + b)*589824;
  const int lane = threadIdx.x & 63, wv = threadIdx.x >> 6;
  const int wr = wv >> 1, wc = wv & 1;
#pragma unroll
  for (int i = 0; i < 4; ++i) {
    const int row0 = mt*128 + wr*64 + i*16 + ((lane >> 4) << 2);
#pragma unroll
    for (int j = 0; j < 4; ++j) {
      const int col = nt*128 + wc*64 + j*16 + (lane & 15);
#pragma unroll
      for (int r = 0; r < 4; ++r)
        out[(size_t)(row0 + r)*2304 + col] = (bf16_t)acc[i][j][r];
    }
  }
}

// ---------------- host ----------------
extern "C" void kernel_launch(void* const* d_in, const int* in_sizes, int n_in,
                              void* d_out, int out_size, void* d_ws, size_t ws_size,
                              hipStream_t stream)
{
  (void)in_sizes; (void)n_in; (void)out_size;
  const float* x   = (const float*)d_in[0];
  const float* y   = (const float*)d_in[1];
  const float* wcv = (const float*)d_in[2];
  const float* bg  = (const float*)d_in[3];
  const float* bb  = (const float*)d_in[4];
  const float* bm  = (const float*)d_in[5];
  const float* bvv = (const float*)d_in[6];
  const float* w1  = (const float*)d_in[7];
  const float* w2  = (const float*)d_in[8];
  float* out = (float*)d_out;
  char* ws = (char*)d_ws;
  if (ws_size < WS_NEED) return;

  bf16_t* xp   = (bf16_t*)(ws + OFF_XP);
  bf16_t* yp   = (bf16_t*)(ws + OFF_YP);
  bf16_t* wqs  = (bf16_t*)(ws + OFF_WQS);
  bf16_t* wvT  = (bf16_t*)(ws + OFF_WVT);
  bf16_t* w1b  = (bf16_t*)(ws + OFF_W1B);
  bf16_t* w2b  = (bf16_t*)(ws + OFF_W2B);
  float*  shq  = (float*)(ws + OFF_SHQ);
  float*  shv  = (float*)(ws + OFF_SHV);
  bf16_t* qk   = (bf16_t*)(ws + OFF_QK);
  bf16_t* pt   = (bf16_t*)(ws + OFF_PT);
  bf16_t* a1   = (bf16_t*)(ws + OFF_A1);
  bf16_t* weff = (bf16_t*)(ws + OFF_WEFF);
  float*  bias = (float*)(ws + OFF_BIAS);

  k_pack     <<<dim3(1089, 8, 2), 256, 0, stream>>>(x, y, xp, yp);
  k_prep_wq  <<<dim3(4096), 256, 0, stream>>>(wcv, bg, bb, bm, bvv, wqs, shq);
  k_prep_wv  <<<dim3(32, 16, 2), 256, 0, stream>>>(wcv, bg, bvv, wvT);
  k_small    <<<dim3(520), 256, 0, stream>>>(w1, w2, bg, bb, bm, bvv, w1b, w2b, shv);
  k_conv_qk7 <<<dim3(512), 512, 0, stream>>>(wqs, xp, yp, qk, shq);
  k_sp       <<<dim3(2, 32, 2), 512, 0, stream>>>(qk, pt);
  k_gemm_a   <<<dim3(4, 32, 2), 256, 0, stream>>>(w1b, w2b, pt, a1);
  k_bias     <<<dim3(64, 8, 2), 256, 0, stream>>>(a1, shv, bias);
  k_gemm_weff<<<dim3(36, 8, 2), 256, 0, stream>>>(a1, wvT, weff);
  k_conv_out7<<<dim3(256), 512, 0, stream>>>(weff, xp, yp, bias, out);
}

// Round 17
// 305.420 us; speedup vs baseline: 1.1998x; 1.0416x over previous
//
#include <hip/hip_runtime.h>
#include <stdint.h>

typedef __bf16 bf16_t;
typedef __bf16 bf16x8 __attribute__((ext_vector_type(8)));
typedef float f32x4 __attribute__((ext_vector_type(4)));

#define EPSBN 1e-5f

// ---------------- workspace layout (bytes) ----------------
#define OFF_XP   ((size_t)0)
#define SZ_IMG   ((size_t)8*4356*256*2)          // padded NHWC bf16 image, 66x66
#define OFF_YP   (OFF_XP + SZ_IMG)
#define OFF_WQS  (OFF_YP + SZ_IMG)
#define SZ_WQS   ((size_t)4*1024*2304*2)         // scaled QK conv weights [conv][hd][tap*256+c]
#define OFF_WVT  (OFF_WQS + SZ_WQS)
#define SZ_WVT   ((size_t)2*2304*1024*2)         // scaled V weights transposed [br][k'][hd]
#define OFF_W1B  (OFF_WVT + SZ_WVT)
#define SZ_WO    ((size_t)65536*2)
#define OFF_W2B  (OFF_W1B + SZ_WO)
#define OFF_SHQ  (OFF_W2B + SZ_WO)
#define SZ_SHQ   ((size_t)4096*4)                // BN shift for convs 0..3
#define OFF_SHV  (OFF_SHQ + SZ_SHQ)
#define SZ_SHV   ((size_t)2048*4)                // BN shift for convs 4,5
#define OFF_QK   (OFF_SHV + SZ_SHV)
#define SZ_QK    ((size_t)4*8*1024*1024*2)       // Q1,Q2,K1,K2: [conv][b][hd][tok] bf16
#define OFF_S    (OFF_QK + SZ_QK)
#define SZ_S     ((size_t)2*8*4*65536*4)         // (unused after fusion)
#define OFF_PT   (OFF_S + SZ_S)
#define SZ_PT    ((size_t)2*8*4*65536*2)         // p^T bf16 [br][b][h][d][c]  (x0.25, /l folded)
#define OFF_A1   (OFF_PT + SZ_PT)
#define SZ_A1    ((size_t)2*8*256*1024*2)        // A1 bf16 [br][b][e][hd]
#define OFF_WEFF (OFF_A1 + SZ_A1)
#define SZ_WEFF  ((size_t)2*8*256*2304*2)        // Weff bf16 [br][b][e][k']
#define OFF_BIAS (OFF_WEFF + SZ_WEFF)
#define SZ_BIAS  ((size_t)2*8*256*4)
#define WS_NEED  (OFF_BIAS + SZ_BIAS)

__device__ __forceinline__ void gload16(const bf16_t* g, bf16_t* l) {
  __builtin_amdgcn_global_load_lds(
      (const __attribute__((address_space(1))) void*)g,
      (__attribute__((address_space(3))) void*)l,
      16, 0, 0);
}

// staging LDS offsets for the B tile (wave wv owns chunks {wv, wv+4})
__device__ __forceinline__ int lb_off0() { return ((threadIdx.x >> 6)    ) * 512; }
__device__ __forceinline__ int lb_off1() { return ((threadIdx.x >> 6) + 4) * 512; }

#define SBAR0 __builtin_amdgcn_sched_barrier(0)

// ---------------- old GEMM core: 128x128 tile, BK=32, 4 waves (small GEMMs) ----------------
template<int BSRC>
__device__ __forceinline__ void gemm_core(
    const bf16_t* __restrict__ A, int ldA,
    const bf16_t* __restrict__ B, int ldB,
    int m0, int n0, int KT, f32x4 acc[4][4])
{
  __shared__ bf16_t lA[2][4096];
  __shared__ bf16_t lB[2][4096];
  const int tid  = threadIdx.x;
  const int lane = tid & 63;
  const int wv   = tid >> 6;
  const int wr   = wv >> 1, wc = wv & 1;
  const int r4   = lane >> 2;       // 0..15
  const int k8   = (lane & 3) * 8;  // 0,8,16,24

  const bf16_t* gA0 = A + (size_t)(m0 + (wv    )*16 + r4) * ldA + k8;
  const bf16_t* gA1 = A + (size_t)(m0 + (wv + 4)*16 + r4) * ldA + k8;
  const int la0 = (wv    ) * 512;
  const int la1 = (wv + 4) * 512;
  const bf16_t* gB0 = B + (size_t)(n0 + (wv    )*16 + r4) * ldB + k8;
  const bf16_t* gB1 = B + (size_t)(n0 + (wv + 4)*16 + r4) * ldB + k8;
  (void)BSRC;

#pragma unroll
  for (int i = 0; i < 4; ++i)
#pragma unroll
    for (int j = 0; j < 4; ++j)
      acc[i][j] = f32x4{0.f, 0.f, 0.f, 0.f};

  const int lr = lane & 15;
  const int lk = (lane >> 4) * 8;
  int aidx[4], bidx[4];
#pragma unroll
  for (int f = 0; f < 4; ++f) {
    aidx[f] = (wr*64 + f*16 + lr)*32 + lk;
    bidx[f] = (wc*64 + f*16 + lr)*32 + lk;
  }

  auto stage = [&](int bufp, int kt) {
    const int kb = kt * 32;
    gload16(gA0 + kb, &lA[bufp][la0]);
    gload16(gA1 + kb, &lA[bufp][la1]);
    gload16(gB0 + kb, &lB[bufp][lb_off0()]);
    gload16(gB1 + kb, &lB[bufp][lb_off1()]);
  };

  stage(0, 0);
  __syncthreads();
  int buf = 0;
  for (int kt = 0; kt < KT; ++kt) {
    if (kt + 1 < KT) stage(buf ^ 1, kt + 1);
    bf16x8 av[4], bvv[4];
#pragma unroll
    for (int f = 0; f < 4; ++f) av[f]  = *(const bf16x8*)&lA[buf][aidx[f]];
#pragma unroll
    for (int f = 0; f < 4; ++f) bvv[f] = *(const bf16x8*)&lB[buf][bidx[f]];
#pragma unroll
    for (int i = 0; i < 4; ++i)
#pragma unroll
      for (int j = 0; j < 4; ++j)
        acc[i][j] = __builtin_amdgcn_mfma_f32_16x16x32_bf16(av[i], bvv[j], acc[i][j], 0, 0, 0);
    __syncthreads();
    buf ^= 1;
  }
}

// ================= 256x256 conv core: single-barrier tile, 8-step lgkm ladder =================
// (R12/R15 proven structure; hazard audit in prior rounds.)
template<int STRIDE>
__device__ __forceinline__ void conv_m201_core(
    const bf16_t* __restrict__ A, const bf16_t* __restrict__ img,
    int m0, int n0, f32x4 acc[8][4])
{
  __shared__ bf16_t lA[2][2][8192];
  __shared__ bf16_t lB[2][2][8192];
  const int tid  = threadIdx.x;           // 0..511
  const int lane = tid & 63;
  const int w    = tid >> 6;
  const int wm   = w >> 2;                // 0..1
  const int wn   = w & 3;                 // 0..3
  const int wh   = wn >> 1;               // B half
  const int wn1  = wn & 1;

#pragma unroll
  for (int f = 0; f < 8; ++f)
#pragma unroll
    for (int c = 0; c < 4; ++c)
      acc[f][c] = f32x4{0.f, 0.f, 0.f, 0.f};

  const int srow = tid >> 3;                       // 0..63 (chunk row)
  const int swz  = ((tid & 7) ^ (srow & 7)) * 8;   // element offset in 64-k row
  const bf16_t* gAsrc = A + (size_t)(m0 + srow) * 2304 + swz;
  const bf16_t* gBsrc[4];
#pragma unroll
  for (int h = 0; h < 2; ++h)
#pragma unroll
    for (int c = 0; c < 2; ++c) {
      const int tok = n0 + h*128 + c*64 + srow;
      int px;
      if (STRIDE == 1) px = (tok >> 6)*66 + (tok & 63);
      else             px = ((tok >> 5)*2)*66 + (tok & 31)*2;
      gBsrc[h*2 + c] = img + (size_t)px*256 + swz;
    }

  auto stageA = [&](int T1, int h) {
    bf16_t* dst = &lA[T1 & 1][h][0] + tid*8;
    const bf16_t* src = gAsrc + (size_t)(h*128)*2304 + T1*64;
    gload16(src, dst);
    gload16(src + (size_t)64*2304, dst + 4096);
  };
  auto stageB = [&](int T1, int h) {
    const int tap = T1 >> 2;
    const int ky  = (tap >= 6) ? 2 : ((tap >= 3) ? 1 : 0);
    const int kx  = tap - ky*3;
    const int ps  = (ky*66 + kx)*256 + (T1 & 3)*64;
    bf16_t* dst = &lB[T1 & 1][h][0] + tid*8;
    gload16(gBsrc[h*2 + 0] + ps, dst);
    gload16(gBsrc[h*2 + 1] + ps, dst + 4096);
  };

  const int rb  = (lane & 15) * 64;
  const int l7  = lane & 7;
  const int g4  = lane >> 4;
  int rs[2];
  rs[0] = ((    g4) ^ l7) * 8;
  rs[1] = ((4 + g4) ^ l7) * 8;

  stageA(0, 0); stageB(0, 0); stageA(0, 1); stageB(0, 1);
  SBAR0;
  asm volatile("s_waitcnt vmcnt(0)" ::: "memory");
  SBAR0;
  __builtin_amdgcn_s_barrier();

#define MFMA2(F, J, AV) do {                                                  \
    acc[F][J] = __builtin_amdgcn_mfma_f32_16x16x32_bf16(AV[0], bvs[(J)>>1][(J)&1][0], acc[F][J], 0, 0, 0); \
    acc[F][J] = __builtin_amdgcn_mfma_f32_16x16x32_bf16(AV[1], bvs[(J)>>1][(J)&1][1], acc[F][J], 0, 0, 0); \
  } while (0)

  for (int T = 0; T < 36; ++T) {
    const int buf = T & 1;
    const bf16_t* pa = &lA[buf][wm][0];
    const bf16_t* pb = &lB[buf][wh][0];
    bf16x8 avl[4][2], avh[4][2], bvs[2][2][2];
    const bool nt = (T + 1 < 36);

#pragma unroll
    for (int j = 0; j < 2; ++j)
#pragma unroll
      for (int kh = 0; kh < 2; ++kh)
        bvs[0][j][kh] = *(const bf16x8*)(pb + (wn1*4096 + j*1024 + rb + rs[kh]));
    SBAR0;
#pragma unroll
    for (int i = 0; i < 4; ++i)
#pragma unroll
      for (int kh = 0; kh < 2; ++kh)
        avl[i][kh] = *(const bf16x8*)(pa + (i*1024 + rb + rs[kh]));
    SBAR0;
#pragma unroll
    for (int j = 0; j < 2; ++j)
#pragma unroll
      for (int kh = 0; kh < 2; ++kh)
        bvs[1][j][kh] = *(const bf16x8*)(pb + (wn1*4096 + (2+j)*1024 + rb + rs[kh]));
    SBAR0;
#pragma unroll
    for (int i = 0; i < 4; ++i)
#pragma unroll
      for (int kh = 0; kh < 2; ++kh)
        avh[i][kh] = *(const bf16x8*)(pa + ((4+i)*1024 + rb + rs[kh]));
    SBAR0;
    if (nt) { stageA(T+1, 0); stageB(T+1, 0); stageA(T+1, 1); stageB(T+1, 1); }
    SBAR0;

    __builtin_amdgcn_s_setprio(1);
    asm volatile("s_waitcnt lgkmcnt(15)" ::: "memory"); SBAR0;
    MFMA2(0,0,avl[0]); MFMA2(0,1,avl[0]);
    MFMA2(1,0,avl[1]); MFMA2(1,1,avl[1]);
    SBAR0;
    asm volatile("s_waitcnt lgkmcnt(14)" ::: "memory"); SBAR0;
    MFMA2(2,0,avl[2]); MFMA2(2,1,avl[2]);
    SBAR0;
    asm volatile("s_waitcnt lgkmcnt(12)" ::: "memory"); SBAR0;
    MFMA2(3,0,avl[3]); MFMA2(3,1,avl[3]);
    SBAR0;
    asm volatile("s_waitcnt lgkmcnt(8)" ::: "memory"); SBAR0;
#pragma unroll
    for (int i = 0; i < 4; ++i) { MFMA2(i,2,avl[i]); MFMA2(i,3,avl[i]); }
    SBAR0;
    asm volatile("s_waitcnt lgkmcnt(6)" ::: "memory"); SBAR0;
    MFMA2(4,0,avh[0]); MFMA2(4,1,avh[0]);
    SBAR0;
    asm volatile("s_waitcnt lgkmcnt(4)" ::: "memory"); SBAR0;
    MFMA2(5,0,avh[1]); MFMA2(5,1,avh[1]);
    SBAR0;
    asm volatile("s_waitcnt lgkmcnt(2)" ::: "memory"); SBAR0;
    MFMA2(6,0,avh[2]); MFMA2(6,1,avh[2]);
    SBAR0;
    asm volatile("s_waitcnt lgkmcnt(0)" ::: "memory"); SBAR0;
    MFMA2(7,0,avh[3]); MFMA2(7,1,avh[3]);
#pragma unroll
    for (int i = 0; i < 4; ++i) { MFMA2(4+i,2,avh[i]); MFMA2(4+i,3,avh[i]); }
    __builtin_amdgcn_s_setprio(0);
    SBAR0;
    asm volatile("s_waitcnt vmcnt(0)" ::: "memory");
    SBAR0;
    __builtin_amdgcn_s_barrier();
  }
#undef MFMA2
}

// ---------------- QK convs (stride 2) ----------------
__global__ __launch_bounds__(512, 1) void k_conv_qk7(const bf16_t* __restrict__ wqs,
    const bf16_t* __restrict__ xp, const bf16_t* __restrict__ yp,
    bf16_t* __restrict__ qk, const float* __restrict__ shq)
{
  const int n  = blockIdx.x;
  const int b  = n & 7;
  const int r1 = n >> 3;         // 0..63
  const int ci = r1 & 3;
  const int r2 = r1 >> 2;        // 0..15
  const int nt = r2 & 3;
  const int mt = r2 >> 2;        // 0..3
  const int m0 = mt*256, n0 = nt*256;
  const bf16_t* A = wqs + (size_t)ci * 1024 * 2304;
  const bf16_t* img = (((ci == 0) | (ci == 3)) ? xp : yp) + (size_t)b*4356*256;
  f32x4 acc[8][4];
  conv_m201_core<2>(A, img, m0, n0, acc);

  bf16_t* out = qk + (size_t)(ci*8 + b) * 1024 * 1024;
  const float* sh = shq + ci*1024;
  const int lane = threadIdx.x & 63, w = threadIdx.x >> 6;
  const int wm = w >> 2, wn = w & 3;
#pragma unroll
  for (int f = 0; f < 8; ++f) {
    const int row0 = m0 + wm*128 + f*16 + ((lane >> 4) << 2);
    const f32x4 s4 = *(const f32x4*)&sh[row0];
#pragma unroll
    for (int c = 0; c < 4; ++c) {
      const int col = n0 + wn*64 + c*16 + (lane & 15);
#pragma unroll
      for (int r = 0; r < 4; ++r)
        out[(size_t)(row0 + r)*1024 + col] = (bf16_t)(acc[f][c][r] + s4[r]);
    }
  }
}

// ---------------- output convs (stride 1, per-batch weights) ----------------
__global__ __launch_bounds__(512, 1) void k_conv_out7(const bf16_t* __restrict__ weff,
    const bf16_t* __restrict__ xp, const bf16_t* __restrict__ yp,
    const float* __restrict__ bias, float* __restrict__ dout)
{
  const int n  = blockIdx.x;
  const int b  = n & 7;
  const int r1 = n >> 3;         // 0..31
  const int br = r1 & 1;
  const int nt = r1 >> 1;        // 0..15
  const int n0 = nt*256;
  const bf16_t* A = weff + (size_t)(br*8 + b)*589824;
  const bf16_t* img = ((br == 0) ? yp : xp) + (size_t)b*4356*256;   // o1 from y, o2 from x
  f32x4 acc[8][4];
  conv_m201_core<1>(A, img, 0, n0, acc);

  float* outp = dout + (size_t)br*8388608 + (size_t)b*1048576;
  const float* bp = bias + (size_t)(br*8 + b)*256;
  const int lane = threadIdx.x & 63, w = threadIdx.x >> 6;
  const int wm = w >> 2, wn = w & 3;
#pragma unroll
  for (int f = 0; f < 8; ++f) {
    const int e0 = wm*128 + f*16 + ((lane >> 4) << 2);
    const f32x4 bv4 = *(const f32x4*)&bp[e0];
#pragma unroll
    for (int c = 0; c < 4; ++c) {
      const int tok = n0 + wn*64 + c*16 + (lane & 15);
      f32x4 v = acc[f][c] + bv4;
      *(f32x4*)&outp[(size_t)tok*256 + e0] = v;
    }
  }
}

// ================= fused QK^T + softmax + p^T write (R16, proven) =================
__global__ __launch_bounds__(512, 1) void k_sp(const bf16_t* __restrict__ qk,
                                               bf16_t* __restrict__ pt)
{
  const int mt = blockIdx.x;          // 0..1
  const int by = blockIdx.y;          // b*4 + h
  const int br = blockIdx.z;
  const int b = by >> 2, h = by & 3;
  const int ai = (br == 0) ? 1 : 0;   // Q2 / Q1
  const int bi = (br == 0) ? 2 : 3;   // K1 / K2
  const bf16_t* A = qk + ((size_t)(ai*8 + b)*1024 + h*256 + mt*128) * 1024;
  const bf16_t* B = qk + ((size_t)(bi*8 + b)*1024 + h*256) * 1024;

  __shared__ bf16_t lA[2][4096];      // 128 x 32
  __shared__ bf16_t lB[2][8192];      // 256 x 32
  __shared__ float red[4][128];

  const int tid = threadIdx.x, lane = tid & 63, w = tid >> 6;
  const int wm = w >> 2, wn = w & 3;

  f32x4 acc[4][4];
#pragma unroll
  for (int i = 0; i < 4; ++i)
#pragma unroll
    for (int j = 0; j < 4; ++j)
      acc[i][j] = f32x4{0.f, 0.f, 0.f, 0.f};

  const int srow = tid >> 2;                           // 0..127
  const int ksX  = (tid & 3) ^ ((tid >> 3) & 3);
  const bf16_t* gA  = A + (size_t)srow*1024 + ksX*8;
  const bf16_t* gB0 = B + (size_t)srow*1024 + ksX*8;
  const bf16_t* gB1 = B + (size_t)(srow + 128)*1024 + ksX*8;

  auto stage = [&](int p, int buf) {
    gload16(gA  + p*32, &lA[buf][0] + tid*8);
    bf16_t* dB = &lB[buf][0] + tid*8;
    gload16(gB0 + p*32, dB);
    gload16(gB1 + p*32, dB + 4096);
  };

  const int lr    = lane & 15;
  const int slotS = (lane >> 4) ^ ((lane & 6) >> 1);
  int offA[4], offB[4];
#pragma unroll
  for (int f = 0; f < 4; ++f) offA[f] = (wm*64 + f*16 + lr)*32 + slotS*8;
#pragma unroll
  for (int c = 0; c < 4; ++c) offB[c] = (wn*64 + c*16 + lr)*32 + slotS*8;

  stage(0, 0);
  SBAR0;
  asm volatile("s_waitcnt vmcnt(0)" ::: "memory");
  SBAR0;
  __builtin_amdgcn_s_barrier();
  SBAR0;

  for (int p = 0; p < 32; ++p) {
    const int buf = p & 1;
    const bf16_t* pA = &lA[buf][0];
    const bf16_t* pB = &lB[buf][0];
    bf16x8 av[4], bv[4];
    av[0] = *(const bf16x8*)(pA + offA[0]);
    av[1] = *(const bf16x8*)(pA + offA[1]);
#pragma unroll
    for (int c = 0; c < 4; ++c) bv[c] = *(const bf16x8*)(pB + offB[c]);
    SBAR0;
    av[2] = *(const bf16x8*)(pA + offA[2]);
    av[3] = *(const bf16x8*)(pA + offA[3]);
    SBAR0;
    if (p + 1 < 32) stage(p + 1, buf ^ 1);
    SBAR0;
    __builtin_amdgcn_s_setprio(1);
    asm volatile("s_waitcnt lgkmcnt(2)" ::: "memory");
    SBAR0;
#pragma unroll
    for (int f = 0; f < 2; ++f)
#pragma unroll
      for (int c = 0; c < 4; ++c)
        acc[f][c] = __builtin_amdgcn_mfma_f32_16x16x32_bf16(av[f], bv[c], acc[f][c], 0, 0, 0);
    SBAR0;
    asm volatile("s_waitcnt lgkmcnt(0)" ::: "memory");
    SBAR0;
#pragma unroll
    for (int f = 2; f < 4; ++f)
#pragma unroll
      for (int c = 0; c < 4; ++c)
        acc[f][c] = __builtin_amdgcn_mfma_f32_16x16x32_bf16(av[f], bv[c], acc[f][c], 0, 0, 0);
    __builtin_amdgcn_s_setprio(0);
    SBAR0;
    asm volatile("s_waitcnt vmcnt(0)" ::: "memory");
    SBAR0;
    __builtin_amdgcn_s_barrier();
    SBAR0;
  }

  // ---- softmax over d (scale 1/16) ----
  const int g = lane >> 4;
  const int rowb = wm*64 + (lane >> 4)*4;   // + i*16 + r

  f32x4 mr[4];
#pragma unroll
  for (int i = 0; i < 4; ++i) {
#pragma unroll
    for (int r = 0; r < 4; ++r) {
      const float m01 = fmaxf(acc[i][0][r], acc[i][1][r]);
      const float m23 = fmaxf(acc[i][2][r], acc[i][3][r]);
      mr[i][r] = fmaxf(m01, m23);
    }
  }
#pragma unroll
  for (int o = 1; o < 16; o <<= 1)
#pragma unroll
    for (int i = 0; i < 4; ++i)
#pragma unroll
      for (int r = 0; r < 4; ++r)
        mr[i][r] = fmaxf(mr[i][r], __shfl_xor(mr[i][r], o));
  if ((lane & 15) == 0) {
#pragma unroll
    for (int i = 0; i < 4; ++i)
#pragma unroll
      for (int r = 0; r < 4; ++r)
        red[wn][rowb + i*16 + r] = mr[i][r];
  }
  __syncthreads();
  f32x4 mf[4];
#pragma unroll
  for (int i = 0; i < 4; ++i)
#pragma unroll
    for (int r = 0; r < 4; ++r) {
      const int row = rowb + i*16 + r;
      mf[i][r] = fmaxf(fmaxf(red[0][row], red[1][row]), fmaxf(red[2][row], red[3][row]));
    }
  __syncthreads();

  f32x4 sr[4];
#pragma unroll
  for (int i = 0; i < 4; ++i) {
    sr[i] = f32x4{0.f, 0.f, 0.f, 0.f};
#pragma unroll
    for (int j = 0; j < 4; ++j)
#pragma unroll
      for (int r = 0; r < 4; ++r) {
        const float e = __expf((acc[i][j][r] - mf[i][r]) * 0.0625f);
        acc[i][j][r] = e;
        sr[i][r] += e;
      }
  }
#pragma unroll
  for (int o = 1; o < 16; o <<= 1)
#pragma unroll
    for (int i = 0; i < 4; ++i)
#pragma unroll
      for (int r = 0; r < 4; ++r)
        sr[i][r] += __shfl_xor(sr[i][r], o);
  if ((lane & 15) == 0) {
#pragma unroll
    for (int i = 0; i < 4; ++i)
#pragma unroll
      for (int r = 0; r < 4; ++r)
        red[wn][rowb + i*16 + r] = sr[i][r];
  }
  __syncthreads();
  f32x4 inv[4];
#pragma unroll
  for (int i = 0; i < 4; ++i)
#pragma unroll
    for (int r = 0; r < 4; ++r) {
      const int row = rowb + i*16 + r;
      inv[i][r] = 0.25f / (red[0][row] + red[1][row] + red[2][row] + red[3][row]);
    }

  bf16_t* out = pt + ((size_t)(br*8 + b)*4 + h) * 65536;
#pragma unroll
  for (int i = 0; i < 4; ++i) {
    const int c0 = mt*128 + wm*64 + i*16 + (g << 2);
#pragma unroll
    for (int j = 0; j < 4; ++j) {
      const int d = wn*64 + j*16 + (lane & 15);
      bf16_t o4[4];
#pragma unroll
      for (int r = 0; r < 4; ++r) o4[r] = (bf16_t)(acc[i][j][r] * inv[i][r]);
      *(uint64_t*)&out[(size_t)d*256 + c0] = *(const uint64_t*)o4;
    }
  }
}

// ================= merged prep: pack | prep_wq | prep_wv | small =================
// Independent prep work in ONE launch (cuts 3 launch gaps).
// Flattened 1D grid: [0,17424) pack, [17424,21520) prep_wq,
// [21520,22544) prep_wv, [22544,23064) small. 256 threads each.
#define NPACK 17424
#define NWQ   4096
#define NWV   1024
#define NSM   520
__global__ __launch_bounds__(256) void k_prep_all(
    const float* __restrict__ x, const float* __restrict__ y,
    const float* __restrict__ wcv,
    const float* __restrict__ bg, const float* __restrict__ bb,
    const float* __restrict__ bm, const float* __restrict__ bvv,
    const float* __restrict__ w1, const float* __restrict__ w2,
    bf16_t* __restrict__ xp, bf16_t* __restrict__ yp,
    bf16_t* __restrict__ wqs, float* __restrict__ shq,
    bf16_t* __restrict__ wvT,
    bf16_t* __restrict__ w1b, bf16_t* __restrict__ w2b, float* __restrict__ shv)
{
  const int bid = blockIdx.x;
  const int tid = threadIdx.x;

  if (bid < NPACK) {
    // ---- pack + pad: [B,4096,256] f32 -> [B,66,66,256] bf16 ----
    const int bx = bid % 1089;
    const int b  = (bid / 1089) & 7;
    const int im = bid / (1089*8);
    const int pix = bx*4 + (tid >> 6);
    const int c4  = (tid & 63) * 4;
    const int i = pix / 66, j = pix - i*66;
    const float* src = im ? y : x;
    bf16_t* dst = im ? yp : xp;
    float4 v = make_float4(0.f, 0.f, 0.f, 0.f);
    if (i >= 1 && i <= 64 && j >= 1 && j <= 64)
      v = *(const float4*)&src[((size_t)b*4096 + (size_t)(i-1)*64 + (j-1))*256 + c4];
    bf16_t o4[4] = {(bf16_t)v.x, (bf16_t)v.y, (bf16_t)v.z, (bf16_t)v.w};
    *(uint64_t*)&dst[((size_t)b*4356 + pix)*256 + c4] = *(const uint64_t*)o4;
    return;
  }
  if (bid < NPACK + NWQ) {
    // ---- prep_wq: QK conv weights, scaled + layout ----
    const int blk = bid - NPACK;          // ci*1024 + hd
    __shared__ float lw[2304];
    const float* src = wcv + (size_t)blk * 2304;
    for (int t = tid; t < 576; t += 256)
      ((float4*)lw)[t] = ((const float4*)src)[t];
    const float sc = bg[blk] * rsqrtf(bvv[blk] + EPSBN);
    if (tid == 0) shq[blk] = bb[blk] - bm[blk]*sc;
    __syncthreads();
    bf16_t* dst = wqs + (size_t)blk * 2304;
    for (int t = tid; t < 2304; t += 256) {
      const int tap = t >> 8, c = t & 255;
      dst[t] = (bf16_t)(lw[c*9 + tap] * sc);
    }
    return;
  }
  if (bid < NPACK + NWQ + NWV) {
    // ---- prep_wv: V conv weights transposed [br][k'][hd] ----
    const int id2 = bid - NPACK - NWQ;
    const int cch = id2 & 31;
    const int yy  = (id2 >> 5) & 15;
    const int br  = id2 >> 9;
    const int h = yy >> 2, dc = yy & 3;
    __shared__ float lw2[64][72];
    __shared__ float lsc[64];
    const int ci = 4 + br;
    const int c0 = cch*8, d0 = dc*64;
    for (int e = tid; e < 64*72; e += 256) {
      const int dd = e / 72, q = e - dd*72;
      lw2[dd][q] = wcv[(size_t)(ci*1024 + h*256 + d0 + dd)*2304 + c0*9 + q];
    }
    if (tid < 64) {
      const int bnIdx = ci*1024 + h*256 + d0 + tid;
      lsc[tid] = bg[bnIdx] * rsqrtf(bvv[bnIdx] + EPSBN);
    }
    __syncthreads();
    for (int e = tid; e < 72*64; e += 256) {
      const int kq = e >> 6, dd = e & 63;
      const int cc = kq / 9, tap = kq - cc*9;
      const int kp = tap*256 + c0 + cc;
      wvT[(size_t)br*2359296 + (size_t)kp*1024 + h*256 + d0 + dd] =
          (bf16_t)(lw2[dd][cc*9 + tap] * lsc[dd]);
    }
    return;
  }
  {
    // ---- small: w_out -> bf16, shiftV ----
    const int idx = (bid - NPACK - NWQ - NWV)*256 + tid;
    if (idx < 65536) {
      w1b[idx] = (bf16_t)w1[idx];
    } else if (idx < 131072) {
      w2b[idx - 65536] = (bf16_t)w2[idx - 65536];
    } else if (idx < 133120) {
      const int t = idx - 131072;           // br*1024 + hd
      const int bnIdx = 4096 + t;           // (4+br)*1024 + hd
      const float sc = bg[bnIdx] * rsqrtf(bvv[bnIdx] + EPSBN);
      shv[t] = bb[bnIdx] - bm[bnIdx]*sc;
    }
  }
}

// ---------------- A-GEMM: A1[e, h*256+d] = w_out @ p ----------------
__global__ __launch_bounds__(256) void k_gemm_a(const bf16_t* __restrict__ w1b, const bf16_t* __restrict__ w2b,
    const bf16_t* __restrict__ pt, bf16_t* __restrict__ a1)
{
  const int bx = blockIdx.x, by = blockIdx.y, br = blockIdx.z;
  const int mt = bx >> 1, nt = bx & 1;
  const int b = by >> 2, h = by & 3;
  const bf16_t* A  = br ? w2b : w1b;
  const bf16_t* Bp = pt + ((size_t)(br*8 + b)*4 + h) * 65536;
  f32x4 acc[4][4];
  gemm_core<0>(A, 256, Bp, 256, mt*128, nt*128, 8, acc);

  bf16_t* out = a1 + (size_t)(br*8 + b)*262144 + h*256;
  const int lane = threadIdx.x & 63, wv = threadIdx.x >> 6;
  const int wr = wv >> 1, wc = wv & 1;
#pragma unroll
  for (int i = 0; i < 4; ++i) {
    const int row0 = mt*128 + wr*64 + i*16 + ((lane >> 4) << 2);
#pragma unroll
    for (int j = 0; j < 4; ++j) {
      const int col = nt*128 + wc*64 + j*16 + (lane & 15);
#pragma unroll
      for (int r = 0; r < 4; ++r)
        out[(size_t)(row0 + r)*1024 + col] = (bf16_t)acc[i][j][r];
    }
  }
}

// ================= merged Weff GEMM + bias =================
// Both read a1, independent of each other -> one launch.
// [0,576) weff tiles; [576,1600) bias rows. 256 threads each.
__global__ __launch_bounds__(256) void k_weff_bias(const bf16_t* __restrict__ a1,
    const bf16_t* __restrict__ wvT, const float* __restrict__ shv,
    bf16_t* __restrict__ weff, float* __restrict__ bias)
{
  const int bid = blockIdx.x;
  if (bid < 576) {
    const int bx = bid % 36;
    const int b  = (bid / 36) & 7;
    const int br = bid / 288;
    const int mt = bx / 18, nt = bx - mt*18;
    const bf16_t* A  = a1 + (size_t)(br*8 + b)*262144;
    const bf16_t* Bp = wvT + (size_t)br*2359296;
    f32x4 acc[4][4];
    gemm_core<0>(A, 1024, Bp, 1024, mt*128, nt*128, 32, acc);

    bf16_t* out = weff + (size_t)(br*8 + b)*589824;
    const int lane = threadIdx.x & 63, wv = threadIdx.x >> 6;
    const int wr = wv >> 1, wc = wv & 1;
#pragma unroll
    for (int i = 0; i < 4; ++i) {
      const int row0 = mt*128 + wr*64 + i*16 + ((lane >> 4) << 2);
#pragma unroll
      for (int j = 0; j < 4; ++j) {
        const int col = nt*128 + wc*64 + j*16 + (lane & 15);
#pragma unroll
        for (int r = 0; r < 4; ++r)
          out[(size_t)(row0 + r)*2304 + col] = (bf16_t)acc[i][j][r];
      }
    }
    return;
  }
  {
    const int id2 = bid - 576;
    const int ex = id2 & 63;
    const int b  = (id2 >> 6) & 7;
    const int br = id2 >> 9;
    const int wv = threadIdx.x >> 6, lane = threadIdx.x & 63;
    const int e = ex*4 + wv;
    const bf16_t* row = a1 + ((size_t)(br*8 + b)*256 + e)*1024;
    const float* sv = shv + br*1024;
    float acc = 0.f;
#pragma unroll
    for (int t = 0; t < 16; ++t) {
      const int idx = t*64 + lane;
      acc += (float)row[idx] * sv[idx];
    }
#pragma unroll
    for (int o = 32; o; o >>= 1) acc += __shfl_xor(acc, o);
    if (lane == 0) bias[(size_t)(br*8 + b)*256 + e] = acc;
  }
}

// ---------------- host ----------------
extern "C" void kernel_launch(void* const* d_in, const int* in_sizes, int n_in,
                              void* d_out, int out_size, void* d_ws, size_t ws_size,
                              hipStream_t stream)
{
  (void)in_sizes; (void)n_in; (void)out_size;
  const float* x   = (const float*)d_in[0];
  const float* y   = (const float*)d_in[1];
  const float* wcv = (const float*)d_in[2];
  const float* bg  = (const float*)d_in[3];
  const float* bb  = (const float*)d_in[4];
  const float* bm  = (const float*)d_in[5];
  const float* bvv = (const float*)d_in[6];
  const float* w1  = (const float*)d_in[7];
  const float* w2  = (const float*)d_in[8];
  float* out = (float*)d_out;
  char* ws = (char*)d_ws;
  if (ws_size < WS_NEED) return;

  bf16_t* xp   = (bf16_t*)(ws + OFF_XP);
  bf16_t* yp   = (bf16_t*)(ws + OFF_YP);
  bf16_t* wqs  = (bf16_t*)(ws + OFF_WQS);
  bf16_t* wvT  = (bf16_t*)(ws + OFF_WVT);
  bf16_t* w1b  = (bf16_t*)(ws + OFF_W1B);
  bf16_t* w2b  = (bf16_t*)(ws + OFF_W2B);
  float*  shq  = (float*)(ws + OFF_SHQ);
  float*  shv  = (float*)(ws + OFF_SHV);
  bf16_t* qk   = (bf16_t*)(ws + OFF_QK);
  bf16_t* pt   = (bf16_t*)(ws + OFF_PT);
  bf16_t* a1   = (bf16_t*)(ws + OFF_A1);
  bf16_t* weff = (bf16_t*)(ws + OFF_WEFF);
  float*  bias = (float*)(ws + OFF_BIAS);

  k_prep_all <<<dim3(NPACK + NWQ + NWV + NSM), 256, 0, stream>>>(
      x, y, wcv, bg, bb, bm, bvv, w1, w2, xp, yp, wqs, shq, wvT, w1b, w2b, shv);
  k_conv_qk7 <<<dim3(512), 512, 0, stream>>>(wqs, xp, yp, qk, shq);
  k_sp       <<<dim3(2, 32, 2), 512, 0, stream>>>(qk, pt);
  k_gemm_a   <<<dim3(4, 32, 2), 256, 0, stream>>>(w1b, w2b, pt, a1);
  k_weff_bias<<<dim3(1600), 256, 0, stream>>>(a1, wvT, shv, weff, bias);
  k_conv_out7<<<dim3(256), 512, 0, stream>>>(weff, xp, yp, bias, out);
}